// Round 1
// baseline (2887.295 us; speedup 1.0000x reference)
//
#include <hip/hip_runtime.h>
#include <hip/hip_bf16.h>
#include <math.h>

#define S_LEN 4096
#define EMB   1024
#define NH    16
#define HD    64

// ---------------------------------------------------------------------------
// Tiled fp32 GEMM: C[M,N] = A[M,K] * B[K,N] + bias[N]
// 128x128 tile, BK=16, 256 threads, 8x8 acc per thread.
// ---------------------------------------------------------------------------
#define TM 128
#define TN 128
#define TK 16

__global__ __launch_bounds__(256, 1)
void gemm_bias_kernel(const float* __restrict__ A, const float* __restrict__ B,
                      const float* __restrict__ bias, float* __restrict__ C,
                      int M, int N, int K) {
    __shared__ float As[TK][TM];   // [k][m] so a-frag is contiguous in m
    __shared__ float Bs[TK][TN];   // [k][n]

    const int tid = threadIdx.x;
    const int bm = blockIdx.x * TM;
    const int bn = blockIdx.y * TN;
    const int tx = tid & 15;        // n direction
    const int ty = tid >> 4;        // m direction
    const int tm = ty * 8;
    const int tn = tx * 8;

    float acc[8][8];
    #pragma unroll
    for (int i = 0; i < 8; i++)
        #pragma unroll
        for (int j = 0; j < 8; j++) acc[i][j] = 0.f;

    // global load indices
    const int arow = tid >> 1;            // 0..127
    const int acol = (tid & 1) * 8;       // 0 or 8
    const int brow = tid >> 4;            // 0..15
    const int bcol = (tid & 15) * 8;      // 0..120

    for (int k0 = 0; k0 < K; k0 += TK) {
        // A tile: rows bm..bm+127, cols k0..k0+15
        {
            const float* ap = A + (size_t)(bm + arow) * K + k0 + acol;
            #pragma unroll
            for (int i = 0; i < 8; i++) As[acol + i][arow] = ap[i];
        }
        // B tile: rows k0..k0+15, cols bn..bn+127
        {
            const float* bp = B + (size_t)(k0 + brow) * N + bn + bcol;
            #pragma unroll
            for (int i = 0; i < 8; i++) Bs[brow][bcol + i] = bp[i];
        }
        __syncthreads();

        #pragma unroll
        for (int k = 0; k < TK; k++) {
            float a_frag[8], b_frag[8];
            #pragma unroll
            for (int i = 0; i < 8; i++) a_frag[i] = As[k][tm + i];
            #pragma unroll
            for (int i = 0; i < 8; i++) b_frag[i] = Bs[k][tn + i];
            #pragma unroll
            for (int i = 0; i < 8; i++)
                #pragma unroll
                for (int j = 0; j < 8; j++)
                    acc[i][j] = fmaf(a_frag[i], b_frag[j], acc[i][j]);
        }
        __syncthreads();
    }

    #pragma unroll
    for (int i = 0; i < 8; i++) {
        const int row = bm + tm + i;
        float* cp = C + (size_t)row * N + bn + tn;
        #pragma unroll
        for (int j = 0; j < 8; j++)
            cp[j] = acc[i][j] + bias[bn + tn + j];
    }
}

// ---------------------------------------------------------------------------
// RoPE applied in place to q and k halves of qkv [S, 3*EMB].
// One thread per (s, h, i) pair with i in [0,32): rotates (i, i+32).
// ---------------------------------------------------------------------------
__global__ __launch_bounds__(256)
void rope_kernel(float* __restrict__ qkv) {
    const int idx = blockIdx.x * blockDim.x + threadIdx.x; // S*NH*32 total
    const int i = idx & 31;
    const int h = (idx >> 5) & (NH - 1);
    const int s = idx >> 9;

    // inv_freq = 10000^(-i/32) = 2^(-i * log2(10000)/32)
    const float inv_freq = exp2f(-(float)i * (13.287712379549449f / 32.0f));
    const float ang = (float)s * inv_freq;
    float sn, cs;
    sincosf(ang, &sn, &cs);

    size_t base = (size_t)s * (3 * EMB) + h * HD;
    // q
    {
        float t1 = qkv[base + i], t2 = qkv[base + i + 32];
        qkv[base + i]      = t1 * cs - t2 * sn;
        qkv[base + i + 32] = t2 * cs + t1 * sn;
    }
    // k
    base += EMB;
    {
        float t1 = qkv[base + i], t2 = qkv[base + i + 32];
        qkv[base + i]      = t1 * cs - t2 * sn;
        qkv[base + i + 32] = t2 * cs + t1 * sn;
    }
}

// ---------------------------------------------------------------------------
// Flash attention, fp32. One thread per query row; block = 256 rows of one
// head. K/V staged in LDS in 64-key tiles; online softmax with lazy rescale.
// Causal: key j allowed iff j <= my_row (mask input is deterministic triu).
// ---------------------------------------------------------------------------
#define KTILE 64
#define KPAD  68   // padded row stride (floats) to spread store banks

__global__ __launch_bounds__(256, 1)
void flash_kernel(const float* __restrict__ qkv, float* __restrict__ ctx) {
    __shared__ float Ks[KTILE][KPAD];
    __shared__ float Vs[KTILE][KPAD];

    const int h = blockIdx.y;
    const int q0 = blockIdx.x * 256;
    const int tid = threadIdx.x;
    const int my_row = q0 + tid;

    // load q row, pre-scaled by 1/sqrt(D)
    float q[HD];
    {
        const float* qp = qkv + (size_t)my_row * (3 * EMB) + h * HD;
        const float4* q4 = (const float4*)qp;
        #pragma unroll
        for (int d4 = 0; d4 < HD / 4; d4++) {
            float4 v = q4[d4];
            q[4 * d4 + 0] = v.x * 0.125f;
            q[4 * d4 + 1] = v.y * 0.125f;
            q[4 * d4 + 2] = v.z * 0.125f;
            q[4 * d4 + 3] = v.w * 0.125f;
        }
    }

    float o[HD];
    #pragma unroll
    for (int d = 0; d < HD; d++) o[d] = 0.f;
    float m = -1e30f, l = 0.f;

    const int ktiles = (q0 + 256) / KTILE;  // keys 0 .. q0+255
    const int ldr = tid >> 2;               // staging row 0..63
    const int ldc = (tid & 3) * 16;         // staging col 0,16,32,48

    for (int kt = 0; kt < ktiles; kt++) {
        const int kbase = kt * KTILE;
        __syncthreads();
        // stage K and V tiles (64 rows x 64 floats each; 16 floats/thread)
        {
            const float* kp = qkv + (size_t)(kbase + ldr) * (3 * EMB) + EMB + h * HD + ldc;
            const float* vp = kp + EMB;
            #pragma unroll
            for (int i = 0; i < 4; i++)
                *(float4*)&Ks[ldr][ldc + 4 * i] = *(const float4*)(kp + 4 * i);
            #pragma unroll
            for (int i = 0; i < 4; i++)
                *(float4*)&Vs[ldr][ldc + 4 * i] = *(const float4*)(vp + 4 * i);
        }
        __syncthreads();

        const int jmax = min(KTILE, my_row - kbase + 1);
        for (int j = 0; j < jmax; j++) {
            // score = q . K[j]
            const float4* kr = (const float4*)&Ks[j][0];
            float s0 = 0.f, s1 = 0.f, s2 = 0.f, s3 = 0.f;
            #pragma unroll
            for (int d4 = 0; d4 < HD / 4; d4++) {
                float4 kv = kr[d4];
                s0 = fmaf(q[4 * d4 + 0], kv.x, s0);
                s1 = fmaf(q[4 * d4 + 1], kv.y, s1);
                s2 = fmaf(q[4 * d4 + 2], kv.z, s2);
                s3 = fmaf(q[4 * d4 + 3], kv.w, s3);
            }
            const float s = (s0 + s1) + (s2 + s3);

            const float mnew = fmaxf(m, s);
            if (mnew > m) {   // lazy rescale — rare after warm-up
                const float c = __expf(m - mnew);
                l *= c;
                #pragma unroll
                for (int d = 0; d < HD; d++) o[d] *= c;
                m = mnew;
            }
            const float p = __expf(s - m);
            l += p;

            const float4* vr = (const float4*)&Vs[j][0];
            #pragma unroll
            for (int d4 = 0; d4 < HD / 4; d4++) {
                float4 vv = vr[d4];
                o[4 * d4 + 0] = fmaf(p, vv.x, o[4 * d4 + 0]);
                o[4 * d4 + 1] = fmaf(p, vv.y, o[4 * d4 + 1]);
                o[4 * d4 + 2] = fmaf(p, vv.z, o[4 * d4 + 2]);
                o[4 * d4 + 3] = fmaf(p, vv.w, o[4 * d4 + 3]);
            }
        }
    }

    const float inv_l = 1.0f / l;
    float* op = ctx + (size_t)my_row * EMB + h * HD;
    float4* o4 = (float4*)op;
    #pragma unroll
    for (int d4 = 0; d4 < HD / 4; d4++) {
        float4 v;
        v.x = o[4 * d4 + 0] * inv_l;
        v.y = o[4 * d4 + 1] * inv_l;
        v.z = o[4 * d4 + 2] * inv_l;
        v.w = o[4 * d4 + 3] * inv_l;
        o4[d4] = v;
    }
}

// ---------------------------------------------------------------------------
extern "C" void kernel_launch(void* const* d_in, const int* in_sizes, int n_in,
                              void* d_out, int out_size, void* d_ws, size_t ws_size,
                              hipStream_t stream) {
    const float* x      = (const float*)d_in[0];
    // d_in[1] is the causal mask — deterministic, handled arithmetically.
    const float* wqkv_w = (const float*)d_in[2];
    const float* wqkv_b = (const float*)d_in[3];
    const float* out_w  = (const float*)d_in[4];
    const float* out_b  = (const float*)d_in[5];
    float* out = (float*)d_out;

    float* qkv = (float*)d_ws;                       // [S, 3*EMB]  48 MB
    float* ctx = qkv + (size_t)S_LEN * 3 * EMB;      // [S, EMB]    16 MB

    dim3 blk(256);

    // qkv = x @ wqkv_w + wqkv_b
    gemm_bias_kernel<<<dim3(S_LEN / TM, (3 * EMB) / TN), blk, 0, stream>>>(
        x, wqkv_w, wqkv_b, qkv, S_LEN, 3 * EMB, EMB);

    // RoPE on q,k
    rope_kernel<<<dim3((S_LEN * NH * 32) / 256), blk, 0, stream>>>(qkv);

    // flash attention -> ctx
    flash_kernel<<<dim3(S_LEN / 256, NH), blk, 0, stream>>>(qkv, ctx);

    // out = ctx @ out_w + out_b
    gemm_bias_kernel<<<dim3(S_LEN / TM, EMB / TN), blk, 0, stream>>>(
        ctx, out_w, out_b, out, S_LEN, EMB, EMB);
}

// Round 2
// 909.718 us; speedup vs baseline: 3.1738x; 3.1738x over previous
//
#include <hip/hip_runtime.h>
#include <hip/hip_bf16.h>
#include <math.h>

#define S_LEN 4096
#define EMB   1024
#define NH    16
#define HD    64

typedef short          bfrag __attribute__((ext_vector_type(8)));  // 8 bf16
typedef float          ffrag __attribute__((ext_vector_type(4)));  // 4 f32
typedef unsigned short us8   __attribute__((ext_vector_type(8)));

__device__ inline unsigned short f2bf(float f) {
    union { float f; unsigned u; } v; v.f = f;
    unsigned r = v.u + 0x7fffu + ((v.u >> 16) & 1u);
    return (unsigned short)(r >> 16);
}

// ---------------------------------------------------------------------------
// Tiled fp32 GEMM: C[M,N] = A[M,K] * B[K,N] + bias[N]  (unchanged this round)
// ---------------------------------------------------------------------------
#define TM 128
#define TN 128
#define TK 16

__global__ __launch_bounds__(256, 1)
void gemm_bias_kernel(const float* __restrict__ A, const float* __restrict__ B,
                      const float* __restrict__ bias, float* __restrict__ C,
                      int M, int N, int K) {
    __shared__ float As[TK][TM];
    __shared__ float Bs[TK][TN];

    const int tid = threadIdx.x;
    const int bm = blockIdx.x * TM;
    const int bn = blockIdx.y * TN;
    const int tx = tid & 15;
    const int ty = tid >> 4;
    const int tm = ty * 8;
    const int tn = tx * 8;

    float acc[8][8];
    #pragma unroll
    for (int i = 0; i < 8; i++)
        #pragma unroll
        for (int j = 0; j < 8; j++) acc[i][j] = 0.f;

    const int arow = tid >> 1;
    const int acol = (tid & 1) * 8;
    const int brow = tid >> 4;
    const int bcol = (tid & 15) * 8;

    for (int k0 = 0; k0 < K; k0 += TK) {
        {
            const float* ap = A + (size_t)(bm + arow) * K + k0 + acol;
            #pragma unroll
            for (int i = 0; i < 8; i++) As[acol + i][arow] = ap[i];
        }
        {
            const float* bp = B + (size_t)(k0 + brow) * N + bn + bcol;
            #pragma unroll
            for (int i = 0; i < 8; i++) Bs[brow][bcol + i] = bp[i];
        }
        __syncthreads();

        #pragma unroll
        for (int k = 0; k < TK; k++) {
            float a_frag[8], b_frag[8];
            #pragma unroll
            for (int i = 0; i < 8; i++) a_frag[i] = As[k][tm + i];
            #pragma unroll
            for (int i = 0; i < 8; i++) b_frag[i] = Bs[k][tn + i];
            #pragma unroll
            for (int i = 0; i < 8; i++)
                #pragma unroll
                for (int j = 0; j < 8; j++)
                    acc[i][j] = fmaf(a_frag[i], b_frag[j], acc[i][j]);
        }
        __syncthreads();
    }

    #pragma unroll
    for (int i = 0; i < 8; i++) {
        const int row = bm + tm + i;
        float* cp = C + (size_t)row * N + bn + tn;
        #pragma unroll
        for (int j = 0; j < 8; j++)
            cp[j] = acc[i][j] + bias[bn + tn + j];
    }
}

// ---------------------------------------------------------------------------
// RoPE in place on q,k halves of qkv [S, 3*EMB] (fp32).
// ---------------------------------------------------------------------------
__global__ __launch_bounds__(256)
void rope_kernel(float* __restrict__ qkv) {
    const int idx = blockIdx.x * blockDim.x + threadIdx.x;
    const int i = idx & 31;
    const int h = (idx >> 5) & (NH - 1);
    const int s = idx >> 9;

    const float inv_freq = exp2f(-(float)i * (13.287712379549449f / 32.0f));
    const float ang = (float)s * inv_freq;
    float sn, cs;
    sincosf(ang, &sn, &cs);

    size_t base = (size_t)s * (3 * EMB) + h * HD;
    {
        float t1 = qkv[base + i], t2 = qkv[base + i + 32];
        qkv[base + i]      = t1 * cs - t2 * sn;
        qkv[base + i + 32] = t2 * cs + t1 * sn;
    }
    base += EMB;
    {
        float t1 = qkv[base + i], t2 = qkv[base + i + 32];
        qkv[base + i]      = t1 * cs - t2 * sn;
        qkv[base + i + 32] = t2 * cs + t1 * sn;
    }
}

// ---------------------------------------------------------------------------
// MFMA flash attention (bf16 compute, fp32 accumulate).
// Block = 128 queries x 1 head, 4 waves x 32 queries. K-tiles of 64 keys.
// mfma_f32_16x16x32_bf16:  A[m=lane&15][k=quad*8+j], C: col=lane&15,
// row=quad*4+reg. Scores in exp2 domain (log2e folded into Q scale).
// ---------------------------------------------------------------------------
#define KTILE 64
#define QTILE 128
#define SD    72   // padded LDS row stride (bf16 elems): 2-way banks = free

__global__ __launch_bounds__(256, 1)
void flash_mfma_kernel(const float* __restrict__ qkv, float* __restrict__ ctx) {
    __shared__ unsigned short Ks[KTILE][SD];      // [key][dim]
    __shared__ unsigned short Vt[KTILE][SD];      // [dim][key]
    __shared__ unsigned short Ps[4][32][SD];      // per-wave: Q then P [qrow][*]

    const int h    = blockIdx.y;
    const int qt   = gridDim.x - 1 - blockIdx.x;  // biggest-work blocks first
    const int q0   = qt * QTILE;
    const int tid  = threadIdx.x;
    const int w    = tid >> 6;
    const int lane = tid & 63;
    const int col  = lane & 15;
    const int quad = lane >> 4;
    const int qbase = q0 + w * 32;
    const int qmaxw = qbase + 31;

    // ---- stage Q (scaled by 1/sqrt(D) * log2e) into Ps[own wave] as bf16 ----
    {
        const int qrow = tid >> 1;            // 0..127 (stays in own wave's region)
        const int c0   = (tid & 1) * 32;
        const float* qp = qkv + (size_t)(q0 + qrow) * (3 * EMB) + h * HD + c0;
        const float SC = 0.125f * 1.44269504088896f;
        unsigned short tmp[32];
        #pragma unroll
        for (int i4 = 0; i4 < 8; i4++) {
            float4 v = ((const float4*)qp)[i4];
            tmp[4 * i4 + 0] = f2bf(v.x * SC);
            tmp[4 * i4 + 1] = f2bf(v.y * SC);
            tmp[4 * i4 + 2] = f2bf(v.z * SC);
            tmp[4 * i4 + 3] = f2bf(v.w * SC);
        }
        #pragma unroll
        for (int i8 = 0; i8 < 4; i8++) {
            us8 vv;
            #pragma unroll
            for (int j = 0; j < 8; j++) vv[j] = tmp[8 * i8 + j];
            *(us8*)&Ps[qrow >> 5][qrow & 31][c0 + 8 * i8] = vv;
        }
    }
    __syncthreads();

    // Q fragments: qf[qsub][kstep]
    bfrag qf[2][2];
    #pragma unroll
    for (int i = 0; i < 2; i++)
        #pragma unroll
        for (int ks = 0; ks < 2; ks++)
            qf[i][ks] = *(const bfrag*)&Ps[w][16 * i + col][32 * ks + 8 * quad];

    ffrag o[2][4];
    float mrow[2][4], lrow[2][4];
    #pragma unroll
    for (int i = 0; i < 2; i++)
        #pragma unroll
        for (int d4 = 0; d4 < 4; d4++)
            #pragma unroll
            for (int r = 0; r < 4; r++) o[i][d4][r] = 0.f;
    #pragma unroll
    for (int i = 0; i < 2; i++)
        #pragma unroll
        for (int r = 0; r < 4; r++) { mrow[i][r] = -3.0e38f; lrow[i][r] = 0.f; }

    const int ntiles = (q0 + QTILE) / KTILE;

    for (int t = 0; t < ntiles; t++) {
        const int kbase = t * KTILE;
        __syncthreads();
        // ---- stage K[key][dim] and V^T[dim][key] as bf16 ----
        {
            const int key = tid >> 2;
            const int c0  = (tid & 3) * 16;
            const float* kp = qkv + (size_t)(kbase + key) * (3 * EMB) + EMB + h * HD + c0;
            const float* vp = kp + EMB;
            unsigned short kb[16];
            #pragma unroll
            for (int i4 = 0; i4 < 4; i4++) {
                float4 v = ((const float4*)kp)[i4];
                kb[4 * i4 + 0] = f2bf(v.x);
                kb[4 * i4 + 1] = f2bf(v.y);
                kb[4 * i4 + 2] = f2bf(v.z);
                kb[4 * i4 + 3] = f2bf(v.w);
            }
            #pragma unroll
            for (int i8 = 0; i8 < 2; i8++) {
                us8 vv;
                #pragma unroll
                for (int j = 0; j < 8; j++) vv[j] = kb[8 * i8 + j];
                *(us8*)&Ks[key][c0 + 8 * i8] = vv;
            }
            #pragma unroll
            for (int i4 = 0; i4 < 4; i4++) {
                float4 v = ((const float4*)vp)[i4];
                Vt[c0 + 4 * i4 + 0][key] = f2bf(v.x);
                Vt[c0 + 4 * i4 + 1][key] = f2bf(v.y);
                Vt[c0 + 4 * i4 + 2][key] = f2bf(v.z);
                Vt[c0 + 4 * i4 + 3][key] = f2bf(v.w);
            }
        }
        __syncthreads();

        if (kbase <= qmaxw) {
            // ---- S = Q K^T ----
            ffrag s[2][4];
            #pragma unroll
            for (int i = 0; i < 2; i++)
                #pragma unroll
                for (int t4 = 0; t4 < 4; t4++)
                    #pragma unroll
                    for (int r = 0; r < 4; r++) s[i][t4][r] = 0.f;

            #pragma unroll
            for (int ks = 0; ks < 2; ks++) {
                bfrag kf[4];
                #pragma unroll
                for (int t4 = 0; t4 < 4; t4++)
                    kf[t4] = *(const bfrag*)&Ks[16 * t4 + col][32 * ks + 8 * quad];
                #pragma unroll
                for (int i = 0; i < 2; i++)
                    #pragma unroll
                    for (int t4 = 0; t4 < 4; t4++)
                        s[i][t4] = __builtin_amdgcn_mfma_f32_16x16x32_bf16(
                            qf[i][ks], kf[t4], s[i][t4], 0, 0, 0);
            }

            // ---- causal mask (key > query -> -inf) ----
            #pragma unroll
            for (int i = 0; i < 2; i++) {
                const int qrow0 = qbase + 16 * i + 4 * quad;
                #pragma unroll
                for (int t4 = 0; t4 < 4; t4++) {
                    const int key = kbase + 16 * t4 + col;
                    #pragma unroll
                    for (int r = 0; r < 4; r++)
                        if (key > qrow0 + r) s[i][t4][r] = -3.0e38f;
                }
            }

            // ---- online softmax (exp2 domain) ----
            #pragma unroll
            for (int i = 0; i < 2; i++) {
                float rmax[4], rsum[4];
                #pragma unroll
                for (int r = 0; r < 4; r++)
                    rmax[r] = fmaxf(fmaxf(s[i][0][r], s[i][1][r]),
                                    fmaxf(s[i][2][r], s[i][3][r]));
                #pragma unroll
                for (int d = 1; d < 16; d <<= 1)
                    #pragma unroll
                    for (int r = 0; r < 4; r++)
                        rmax[r] = fmaxf(rmax[r], __shfl_xor(rmax[r], d, 64));

                #pragma unroll
                for (int r = 0; r < 4; r++) {
                    float mold = mrow[i][r];
                    float mnew = fmaxf(mold, rmax[r]);
                    float corr = exp2f(mold - mnew);
                    mrow[i][r] = mnew;
                    lrow[i][r] *= corr;
                    #pragma unroll
                    for (int d4 = 0; d4 < 4; d4++) o[i][d4][r] *= corr;
                }
                #pragma unroll
                for (int t4 = 0; t4 < 4; t4++)
                    #pragma unroll
                    for (int r = 0; r < 4; r++)
                        s[i][t4][r] = exp2f(s[i][t4][r] - mrow[i][r]);
                #pragma unroll
                for (int r = 0; r < 4; r++)
                    rsum[r] = (s[i][0][r] + s[i][1][r]) + (s[i][2][r] + s[i][3][r]);
                #pragma unroll
                for (int d = 1; d < 16; d <<= 1)
                    #pragma unroll
                    for (int r = 0; r < 4; r++)
                        rsum[r] += __shfl_xor(rsum[r], d, 64);
                #pragma unroll
                for (int r = 0; r < 4; r++) lrow[i][r] += rsum[r];

                // write P (bf16) to own wave's LDS region [qrow][key]
                #pragma unroll
                for (int t4 = 0; t4 < 4; t4++)
                    #pragma unroll
                    for (int r = 0; r < 4; r++)
                        Ps[w][16 * i + 4 * quad + r][16 * t4 + col] = f2bf(s[i][t4][r]);
            }

            // ---- O += P V ----
            #pragma unroll
            for (int ks = 0; ks < 2; ks++) {
                bfrag pf[2], vf[4];
                #pragma unroll
                for (int i = 0; i < 2; i++)
                    pf[i] = *(const bfrag*)&Ps[w][16 * i + col][32 * ks + 8 * quad];
                #pragma unroll
                for (int d4 = 0; d4 < 4; d4++)
                    vf[d4] = *(const bfrag*)&Vt[16 * d4 + col][32 * ks + 8 * quad];
                #pragma unroll
                for (int i = 0; i < 2; i++)
                    #pragma unroll
                    for (int d4 = 0; d4 < 4; d4++)
                        o[i][d4] = __builtin_amdgcn_mfma_f32_16x16x32_bf16(
                            pf[i], vf[d4], o[i][d4], 0, 0, 0);
            }
        }
    }

    // ---- epilogue: normalize, write ctx (fp32) ----
    #pragma unroll
    for (int i = 0; i < 2; i++) {
        float inv[4];
        #pragma unroll
        for (int r = 0; r < 4; r++) inv[r] = 1.0f / lrow[i][r];
        const int row0 = qbase + 16 * i + 4 * quad;
        #pragma unroll
        for (int d4 = 0; d4 < 4; d4++)
            #pragma unroll
            for (int r = 0; r < 4; r++)
                ctx[(size_t)(row0 + r) * EMB + h * HD + 16 * d4 + col] =
                    o[i][d4][r] * inv[r];
    }
}

// ---------------------------------------------------------------------------
extern "C" void kernel_launch(void* const* d_in, const int* in_sizes, int n_in,
                              void* d_out, int out_size, void* d_ws, size_t ws_size,
                              hipStream_t stream) {
    const float* x      = (const float*)d_in[0];
    const float* wqkv_w = (const float*)d_in[2];
    const float* wqkv_b = (const float*)d_in[3];
    const float* out_w  = (const float*)d_in[4];
    const float* out_b  = (const float*)d_in[5];
    float* out = (float*)d_out;

    float* qkv = (float*)d_ws;                       // [S, 3*EMB]  48 MB
    float* ctx = qkv + (size_t)S_LEN * 3 * EMB;      // [S, EMB]    16 MB

    dim3 blk(256);

    gemm_bias_kernel<<<dim3(S_LEN / TM, (3 * EMB) / TN), blk, 0, stream>>>(
        x, wqkv_w, wqkv_b, qkv, S_LEN, 3 * EMB, EMB);

    rope_kernel<<<dim3((S_LEN * NH * 32) / 256), blk, 0, stream>>>(qkv);

    flash_mfma_kernel<<<dim3(S_LEN / QTILE, NH), blk, 0, stream>>>(qkv, ctx);

    gemm_bias_kernel<<<dim3(S_LEN / TM, EMB / TN), blk, 0, stream>>>(
        ctx, out_w, out_b, out, S_LEN, EMB, EMB);
}

// Round 3
// 363.394 us; speedup vs baseline: 7.9454x; 2.5034x over previous
//
#include <hip/hip_runtime.h>
#include <hip/hip_bf16.h>
#include <math.h>

#define S_LEN 4096
#define EMB   1024
#define E3    3072
#define NH    16
#define HD    64

typedef unsigned short u16;
typedef short          bfrag __attribute__((ext_vector_type(8)));  // 8 bf16
typedef float          ffrag __attribute__((ext_vector_type(4)));  // 4 f32
typedef unsigned short us8   __attribute__((ext_vector_type(8)));
typedef unsigned short us4   __attribute__((ext_vector_type(4)));

__device__ __forceinline__ u16 f2bf(float f) {
    union { float f; unsigned u; } v; v.f = f;
    unsigned r = v.u + 0x7fffu + ((v.u >> 16) & 1u);
    return (u16)(r >> 16);
}
__device__ __forceinline__ float bf2f(u16 b) {
    union { unsigned u; float f; } v; v.u = ((unsigned)b) << 16;
    return v.f;
}
// async global->LDS, 16B per lane; LDS dest = uniform base + lane*16
__device__ __forceinline__ void gld16(const void* g, void* l) {
    __builtin_amdgcn_global_load_lds(
        (const __attribute__((address_space(1))) unsigned int*)g,
        (__attribute__((address_space(3))) unsigned int*)l, 16, 0, 0);
}

// ---------------------------------------------------------------------------
// cast fp32 -> bf16, 8 elems/thread
// ---------------------------------------------------------------------------
__global__ __launch_bounds__(256)
void cast_bf16_kernel(const float* __restrict__ in, u16* __restrict__ out) {
    const size_t i = ((size_t)blockIdx.x * 256 + threadIdx.x) * 8;
    float4 a = *(const float4*)(in + i);
    float4 b = *(const float4*)(in + i + 4);
    us8 o;
    o[0]=f2bf(a.x); o[1]=f2bf(a.y); o[2]=f2bf(a.z); o[3]=f2bf(a.w);
    o[4]=f2bf(b.x); o[5]=f2bf(b.y); o[6]=f2bf(b.z); o[7]=f2bf(b.w);
    *(us8*)(out + i) = o;
}

// ---------------------------------------------------------------------------
// transpose+cast: in [R][C] fp32 -> out [C][R] bf16.  64x64 tiles.
// ---------------------------------------------------------------------------
__global__ __launch_bounds__(256)
void transpose_cast_kernel(const float* __restrict__ in, u16* __restrict__ out,
                           int R, int C) {
    __shared__ u16 T[64][72];
    const int r0 = blockIdx.x * 64, c0 = blockIdx.y * 64;
    const int t = threadIdx.x;
    const int rr = t >> 2, cc = (t & 3) * 16;

    const float* ip = in + (size_t)(r0 + rr) * C + c0 + cc;
    u16 tmp[16];
    #pragma unroll
    for (int i4 = 0; i4 < 4; i4++) {
        float4 v = ((const float4*)ip)[i4];
        tmp[4*i4+0]=f2bf(v.x); tmp[4*i4+1]=f2bf(v.y);
        tmp[4*i4+2]=f2bf(v.z); tmp[4*i4+3]=f2bf(v.w);
    }
    #pragma unroll
    for (int i8 = 0; i8 < 2; i8++) {
        us8 vv;
        #pragma unroll
        for (int j = 0; j < 8; j++) vv[j] = tmp[8*i8+j];
        *(us8*)&T[rr][cc + 8*i8] = vv;
    }
    __syncthreads();

    const int oc = t >> 2, orr = (t & 3) * 16;
    u16 ot[16];
    #pragma unroll
    for (int j = 0; j < 16; j++) ot[j] = T[orr + j][oc];
    u16* op = out + (size_t)(c0 + oc) * R + r0 + orr;
    #pragma unroll
    for (int i8 = 0; i8 < 2; i8++) {
        us8 vv;
        #pragma unroll
        for (int j = 0; j < 8; j++) vv[j] = ot[8*i8+j];
        *(us8*)(op + 8*i8) = vv;
    }
}

// ---------------------------------------------------------------------------
// transpose V part of qkvb [s][2048 + h*64 + d] -> vt[h][d][s]  (bf16->bf16)
// ---------------------------------------------------------------------------
__global__ __launch_bounds__(256)
void transpose_v_kernel(const u16* __restrict__ qkvb, u16* __restrict__ vt) {
    __shared__ u16 T[64][72];
    const int s0 = blockIdx.x * 64, h = blockIdx.y;
    const int t = threadIdx.x;
    const int rr = t >> 2, cc = (t & 3) * 16;

    const u16* ip = qkvb + (size_t)(s0 + rr) * E3 + 2 * EMB + h * HD + cc;
    *(us8*)&T[rr][cc]     = *(const us8*)ip;
    *(us8*)&T[rr][cc + 8] = *(const us8*)(ip + 8);
    __syncthreads();

    const int od = t >> 2, os = (t & 3) * 16;
    u16 ot[16];
    #pragma unroll
    for (int j = 0; j < 16; j++) ot[j] = T[os + j][od];
    u16* op = vt + ((size_t)h * HD + od) * S_LEN + s0 + os;
    #pragma unroll
    for (int i8 = 0; i8 < 2; i8++) {
        us8 vv;
        #pragma unroll
        for (int j = 0; j < 8; j++) vv[j] = ot[8*i8+j];
        *(us8*)(op + 8*i8) = vv;
    }
}

// ---------------------------------------------------------------------------
// RoPE in place on bf16 qkv; q additionally scaled by 1/sqrt(D)*log2e.
// ---------------------------------------------------------------------------
__global__ __launch_bounds__(256)
void rope_bf16_kernel(u16* __restrict__ qkvb) {
    const int idx = blockIdx.x * blockDim.x + threadIdx.x;
    const int i = idx & 31;
    const int h = (idx >> 5) & (NH - 1);
    const int s = idx >> 9;

    const float inv_freq = exp2f(-(float)i * (13.287712379549449f / 32.0f));
    float sn, cs;
    sincosf((float)s * inv_freq, &sn, &cs);
    const float SC = 0.125f * 1.44269504088896f;

    size_t base = (size_t)s * E3 + h * HD;
    {
        float t1 = bf2f(qkvb[base + i]), t2 = bf2f(qkvb[base + i + 32]);
        qkvb[base + i]      = f2bf((t1 * cs - t2 * sn) * SC);
        qkvb[base + i + 32] = f2bf((t2 * cs + t1 * sn) * SC);
    }
    base += EMB;
    {
        float t1 = bf2f(qkvb[base + i]), t2 = bf2f(qkvb[base + i + 32]);
        qkvb[base + i]      = f2bf(t1 * cs - t2 * sn);
        qkvb[base + i + 32] = f2bf(t2 * cs + t1 * sn);
    }
}

// ---------------------------------------------------------------------------
// bf16 MFMA GEMM (m97 structure): C[M,N] = A[M,K] * Bt[N,K]^T + bias
// 128x128 tile, BK=32, 4 waves in 2x2, 4x4 16x16x32 MFMA tiles per wave.
// ---------------------------------------------------------------------------
template <int OUT_BF16>
__global__ __launch_bounds__(256, 2)
void gemm_bt_kernel(const u16* __restrict__ A, const u16* __restrict__ Bt,
                    const float* __restrict__ bias, void* __restrict__ Cv,
                    int M, int N, int K) {
    __shared__ u16 As[128][32];
    __shared__ u16 Bs[128][32];

    const int tid = threadIdx.x;
    const int w = tid >> 6, L = tid & 63;
    const int col = L & 15, quad = L >> 4;
    const int wm = w & 1, wn = w >> 1;
    const int m0 = blockIdx.x * 128, n0 = blockIdx.y * 128;

    ffrag acc[4][4];
    #pragma unroll
    for (int a = 0; a < 4; a++)
        #pragma unroll
        for (int b = 0; b < 4; b++)
            #pragma unroll
            for (int r = 0; r < 4; r++) acc[a][b][r] = 0.f;

    const int srow = L >> 2;       // 0..15 within 16-row group
    const int schk = L & 3;        // 16B chunk (8 bf16)

    for (int k0 = 0; k0 < K; k0 += 32) {
        __syncthreads();
        #pragma unroll
        for (int t = 0; t < 2; t++) {
            const int rg = (2 * w + t) * 16;   // row group base
            gld16(A  + (size_t)(m0 + rg + srow) * K + k0 + schk * 8, &As[rg][0]);
            gld16(Bt + (size_t)(n0 + rg + srow) * K + k0 + schk * 8, &Bs[rg][0]);
        }
        __syncthreads();

        bfrag af[4], bf[4];
        #pragma unroll
        for (int mt = 0; mt < 4; mt++)
            af[mt] = *(const bfrag*)&As[64 * wm + 16 * mt + col][8 * quad];
        #pragma unroll
        for (int nt = 0; nt < 4; nt++)
            bf[nt] = *(const bfrag*)&Bs[64 * wn + 16 * nt + col][8 * quad];
        #pragma unroll
        for (int mt = 0; mt < 4; mt++)
            #pragma unroll
            for (int nt = 0; nt < 4; nt++)
                acc[mt][nt] = __builtin_amdgcn_mfma_f32_16x16x32_bf16(
                    af[mt], bf[nt], acc[mt][nt], 0, 0, 0);
    }

    float bv[4];
    #pragma unroll
    for (int nt = 0; nt < 4; nt++) bv[nt] = bias[n0 + 64 * wn + 16 * nt + col];

    #pragma unroll
    for (int mt = 0; mt < 4; mt++) {
        #pragma unroll
        for (int r = 0; r < 4; r++) {
            const int m = m0 + 64 * wm + 16 * mt + 4 * quad + r;
            #pragma unroll
            for (int nt = 0; nt < 4; nt++) {
                const int n = n0 + 64 * wn + 16 * nt + col;
                const float val = acc[mt][nt][r] + bv[nt];
                if (OUT_BF16) ((u16*)Cv)[(size_t)m * N + n] = f2bf(val);
                else          ((float*)Cv)[(size_t)m * N + n] = val;
            }
        }
    }
}

// ---------------------------------------------------------------------------
// MFMA flash attention v2: S^T = K Q^T, O^T = V^T P^T.  All staging via
// global_load_lds with XOR chunk swizzle (chunk' = chunk ^ (row&7)).
// Block = 128 q x 1 head, 4 waves x 32 q.  Everything bf16, fp32 accum.
// ---------------------------------------------------------------------------
__global__ __launch_bounds__(256, 2)
void flash2_kernel(const u16* __restrict__ qkvb, const u16* __restrict__ vt,
                   u16* __restrict__ ctxb) {
    __shared__ u16 Qs[128][64];
    __shared__ u16 Ks[64][64];
    __shared__ u16 Vs[64][64];
    __shared__ u16 Ps[4][32][72];

    const int h = blockIdx.y;
    const int qt = gridDim.x - 1 - blockIdx.x;   // biggest-work blocks first
    const int q0 = qt * 128;
    const int tid = threadIdx.x;
    const int w = tid >> 6, L = tid & 63;
    const int col = L & 15, quad = L >> 4;
    const int lr = L >> 3, lp = L & 7;
    const int lc = lp ^ lr;                       // logical chunk for staging

    // ---- stage Q (128 rows x 64 bf16), 4 gld per wave ----
    #pragma unroll
    for (int t = 0; t < 4; t++) {
        const int row = 32 * w + 8 * t;
        gld16(qkvb + (size_t)(q0 + row + lr) * E3 + h * HD + lc * 8, &Qs[row][0]);
    }
    __syncthreads();

    bfrag qf[2][2];
    #pragma unroll
    for (int i = 0; i < 2; i++)
        #pragma unroll
        for (int ks = 0; ks < 2; ks++)
            qf[i][ks] = *(const bfrag*)
                &Qs[32 * w + 16 * i + col][(((4 * ks + quad) ^ (col & 7)) * 8)];

    ffrag o[4][2];
    float m[2], l[2];
    #pragma unroll
    for (int d4 = 0; d4 < 4; d4++)
        #pragma unroll
        for (int i = 0; i < 2; i++)
            #pragma unroll
            for (int r = 0; r < 4; r++) o[d4][i][r] = 0.f;
    m[0] = m[1] = -3.0e38f; l[0] = l[1] = 0.f;

    const int qmaxw = q0 + 32 * w + 31;
    const int ntiles = (q0 + 128) / 64;

    for (int t = 0; t < ntiles; t++) {
        const int kb = t * 64;
        __syncthreads();
        #pragma unroll
        for (int u = 0; u < 2; u++) {
            const int row = 16 * w + 8 * u;
            gld16(qkvb + (size_t)(kb + row + lr) * E3 + EMB + h * HD + lc * 8,
                  &Ks[row][0]);
            gld16(vt + ((size_t)h * HD + row + lr) * S_LEN + kb + lc * 8,
                  &Vs[row][0]);
        }
        __syncthreads();
        if (kb > qmaxw) continue;

        // ---- S^T = K Q^T ----
        ffrag st[4][2];
        #pragma unroll
        for (int t4 = 0; t4 < 4; t4++)
            #pragma unroll
            for (int i = 0; i < 2; i++)
                #pragma unroll
                for (int r = 0; r < 4; r++) st[t4][i][r] = 0.f;

        #pragma unroll
        for (int ks = 0; ks < 2; ks++) {
            bfrag kf[4];
            #pragma unroll
            for (int t4 = 0; t4 < 4; t4++)
                kf[t4] = *(const bfrag*)
                    &Ks[16 * t4 + col][(((4 * ks + quad) ^ (col & 7)) * 8)];
            #pragma unroll
            for (int t4 = 0; t4 < 4; t4++)
                #pragma unroll
                for (int i = 0; i < 2; i++)
                    st[t4][i] = __builtin_amdgcn_mfma_f32_16x16x32_bf16(
                        kf[t4], qf[i][ks], st[t4][i], 0, 0, 0);
        }

        // ---- causal mask: key > query -> -inf ----
        #pragma unroll
        for (int i = 0; i < 2; i++) {
            const int qg = q0 + 32 * w + 16 * i + col;
            #pragma unroll
            for (int t4 = 0; t4 < 4; t4++) {
                const int key0 = kb + 16 * t4 + 4 * quad;
                #pragma unroll
                for (int r = 0; r < 4; r++)
                    if (key0 + r > qg) st[t4][i][r] = -3.0e38f;
            }
        }

        // ---- online softmax (exp2 domain), per q = per lane ----
        #pragma unroll
        for (int i = 0; i < 2; i++) {
            float mx = -3.0e38f;
            #pragma unroll
            for (int t4 = 0; t4 < 4; t4++)
                #pragma unroll
                for (int r = 0; r < 4; r++) mx = fmaxf(mx, st[t4][i][r]);
            mx = fmaxf(mx, __shfl_xor(mx, 16, 64));
            mx = fmaxf(mx, __shfl_xor(mx, 32, 64));

            const float mn = fmaxf(m[i], mx);
            const float corr = exp2f(m[i] - mn);
            m[i] = mn;
            l[i] *= corr;
            #pragma unroll
            for (int d4 = 0; d4 < 4; d4++)
                #pragma unroll
                for (int r = 0; r < 4; r++) o[d4][i][r] *= corr;

            float sm = 0.f;
            #pragma unroll
            for (int t4 = 0; t4 < 4; t4++) {
                us4 pk;
                #pragma unroll
                for (int r = 0; r < 4; r++) {
                    const float p = exp2f(st[t4][i][r] - mn);
                    sm += p;
                    pk[r] = f2bf(p);
                }
                *(us4*)&Ps[w][16 * i + col][16 * t4 + 4 * quad] = pk;
            }
            sm += __shfl_xor(sm, 16, 64);
            sm += __shfl_xor(sm, 32, 64);
            l[i] += sm;
        }

        // ---- O^T += V^T P^T ----
        #pragma unroll
        for (int ks = 0; ks < 2; ks++) {
            bfrag vf[4], pf[2];
            #pragma unroll
            for (int d4 = 0; d4 < 4; d4++)
                vf[d4] = *(const bfrag*)
                    &Vs[16 * d4 + col][(((4 * ks + quad) ^ (col & 7)) * 8)];
            #pragma unroll
            for (int i = 0; i < 2; i++)
                pf[i] = *(const bfrag*)&Ps[w][16 * i + col][32 * ks + 8 * quad];
            #pragma unroll
            for (int d4 = 0; d4 < 4; d4++)
                #pragma unroll
                for (int i = 0; i < 2; i++)
                    o[d4][i] = __builtin_amdgcn_mfma_f32_16x16x32_bf16(
                        vf[d4], pf[i], o[d4][i], 0, 0, 0);
        }
    }

    // ---- epilogue: normalize, write ctx bf16 (4 consecutive d per store) ----
    #pragma unroll
    for (int i = 0; i < 2; i++) {
        const float inv = 1.0f / l[i];
        const int qg = q0 + 32 * w + 16 * i + col;
        #pragma unroll
        for (int d4 = 0; d4 < 4; d4++) {
            us4 pk;
            #pragma unroll
            for (int r = 0; r < 4; r++) pk[r] = f2bf(o[d4][i][r] * inv);
            *(us4*)&ctxb[(size_t)qg * EMB + h * HD + 16 * d4 + 4 * quad] = pk;
        }
    }
}

// ---------------------------------------------------------------------------
extern "C" void kernel_launch(void* const* d_in, const int* in_sizes, int n_in,
                              void* d_out, int out_size, void* d_ws, size_t ws_size,
                              hipStream_t stream) {
    const float* x      = (const float*)d_in[0];
    const float* wqkv_w = (const float*)d_in[2];
    const float* wqkv_b = (const float*)d_in[3];
    const float* out_w  = (const float*)d_in[4];
    const float* out_b  = (const float*)d_in[5];
    float* out = (float*)d_out;

    // ws layout (bf16 elements): total 58.7 MB
    u16* qkvb = (u16*)d_ws;                        // [4096][3072]
    u16* ctxb = qkvb + (size_t)S_LEN * E3;         // [4096][1024]
    u16* xb   = ctxb + (size_t)S_LEN * EMB;        // [4096][1024]
    u16* wt   = xb   + (size_t)S_LEN * EMB;        // [3072][1024]
    u16* owt  = wt   + (size_t)E3 * EMB;           // [1024][1024]
    u16* vtb  = owt  + (size_t)EMB * EMB;          // [16][64][4096]

    dim3 blk(256);

    cast_bf16_kernel<<<dim3(S_LEN * EMB / (256 * 8)), blk, 0, stream>>>(x, xb);
    transpose_cast_kernel<<<dim3(EMB / 64, E3 / 64), blk, 0, stream>>>(
        wqkv_w, wt, EMB, E3);
    transpose_cast_kernel<<<dim3(EMB / 64, EMB / 64), blk, 0, stream>>>(
        out_w, owt, EMB, EMB);

    gemm_bt_kernel<1><<<dim3(S_LEN / 128, E3 / 128), blk, 0, stream>>>(
        xb, wt, wqkv_b, qkvb, S_LEN, E3, EMB);

    rope_bf16_kernel<<<dim3(S_LEN * NH * 32 / 256), blk, 0, stream>>>(qkvb);
    transpose_v_kernel<<<dim3(S_LEN / 64, NH), blk, 0, stream>>>(qkvb, vtb);

    flash2_kernel<<<dim3(S_LEN / 128, NH), blk, 0, stream>>>(qkvb, vtb, ctxb);

    gemm_bt_kernel<0><<<dim3(S_LEN / 128, EMB / 128), blk, 0, stream>>>(
        ctxb, owt, out_b, out, S_LEN, EMB, EMB);
}

// Round 4
// 281.406 us; speedup vs baseline: 10.2603x; 1.2914x over previous
//
#include <hip/hip_runtime.h>
#include <hip/hip_bf16.h>
#include <math.h>

#define S_LEN 4096
#define EMB   1024
#define E3    3072
#define NH    16
#define HD    64

typedef unsigned short u16;
typedef short          bfrag __attribute__((ext_vector_type(8)));  // 8 bf16
typedef float          ffrag __attribute__((ext_vector_type(4)));  // 4 f32
typedef unsigned short us8   __attribute__((ext_vector_type(8)));
typedef unsigned short us4   __attribute__((ext_vector_type(4)));

__device__ __forceinline__ u16 f2bf(float f) {
    union { float f; unsigned u; } v; v.f = f;
    unsigned r = v.u + 0x7fffu + ((v.u >> 16) & 1u);
    return (u16)(r >> 16);
}
__device__ __forceinline__ float bf2f(u16 b) {
    union { unsigned u; float f; } v; v.u = ((unsigned)b) << 16;
    return v.f;
}
// pack two f32 -> two bf16 (truncation) in one v_perm_b32
__device__ __forceinline__ unsigned pack_bf16_trunc(float lo, float hi) {
    union { float f; unsigned u; } a, b; a.f = lo; b.f = hi;
    return __builtin_amdgcn_perm(b.u, a.u, 0x07060302u);
}
// async global->LDS, 16B per lane; LDS dest = uniform base + lane*16
__device__ __forceinline__ void gld16(const void* g, void* l) {
    __builtin_amdgcn_global_load_lds(
        (const __attribute__((address_space(1))) unsigned int*)g,
        (__attribute__((address_space(3))) unsigned int*)l, 16, 0, 0);
}

// ---------------------------------------------------------------------------
// cast fp32 -> bf16, 8 elems/thread
// ---------------------------------------------------------------------------
__global__ __launch_bounds__(256)
void cast_bf16_kernel(const float* __restrict__ in, u16* __restrict__ out) {
    const size_t i = ((size_t)blockIdx.x * 256 + threadIdx.x) * 8;
    float4 a = *(const float4*)(in + i);
    float4 b = *(const float4*)(in + i + 4);
    us8 o;
    o[0]=f2bf(a.x); o[1]=f2bf(a.y); o[2]=f2bf(a.z); o[3]=f2bf(a.w);
    o[4]=f2bf(b.x); o[5]=f2bf(b.y); o[6]=f2bf(b.z); o[7]=f2bf(b.w);
    *(us8*)(out + i) = o;
}

// ---------------------------------------------------------------------------
// transpose+cast: in [R][C] fp32 -> out [C][R] bf16.  64x64 tiles.
// ---------------------------------------------------------------------------
__global__ __launch_bounds__(256)
void transpose_cast_kernel(const float* __restrict__ in, u16* __restrict__ out,
                           int R, int C) {
    __shared__ u16 T[64][72];
    const int r0 = blockIdx.x * 64, c0 = blockIdx.y * 64;
    const int t = threadIdx.x;
    const int rr = t >> 2, cc = (t & 3) * 16;

    const float* ip = in + (size_t)(r0 + rr) * C + c0 + cc;
    u16 tmp[16];
    #pragma unroll
    for (int i4 = 0; i4 < 4; i4++) {
        float4 v = ((const float4*)ip)[i4];
        tmp[4*i4+0]=f2bf(v.x); tmp[4*i4+1]=f2bf(v.y);
        tmp[4*i4+2]=f2bf(v.z); tmp[4*i4+3]=f2bf(v.w);
    }
    #pragma unroll
    for (int i8 = 0; i8 < 2; i8++) {
        us8 vv;
        #pragma unroll
        for (int j = 0; j < 8; j++) vv[j] = tmp[8*i8+j];
        *(us8*)&T[rr][cc + 8*i8] = vv;
    }
    __syncthreads();

    const int oc = t >> 2, orr = (t & 3) * 16;
    u16 ot[16];
    #pragma unroll
    for (int j = 0; j < 16; j++) ot[j] = T[orr + j][oc];
    u16* op = out + (size_t)(c0 + oc) * R + r0 + orr;
    #pragma unroll
    for (int i8 = 0; i8 < 2; i8++) {
        us8 vv;
        #pragma unroll
        for (int j = 0; j < 8; j++) vv[j] = ot[8*i8+j];
        *(us8*)(op + 8*i8) = vv;
    }
}

// ---------------------------------------------------------------------------
// transpose V part of qkvb [s][2048 + h*64 + d] -> vt[h][d][s]  (bf16->bf16)
// ---------------------------------------------------------------------------
__global__ __launch_bounds__(256)
void transpose_v_kernel(const u16* __restrict__ qkvb, u16* __restrict__ vt) {
    __shared__ u16 T[64][72];
    const int s0 = blockIdx.x * 64, h = blockIdx.y;
    const int t = threadIdx.x;
    const int rr = t >> 2, cc = (t & 3) * 16;

    const u16* ip = qkvb + (size_t)(s0 + rr) * E3 + 2 * EMB + h * HD + cc;
    *(us8*)&T[rr][cc]     = *(const us8*)ip;
    *(us8*)&T[rr][cc + 8] = *(const us8*)(ip + 8);
    __syncthreads();

    const int od = t >> 2, os = (t & 3) * 16;
    u16 ot[16];
    #pragma unroll
    for (int j = 0; j < 16; j++) ot[j] = T[os + j][od];
    u16* op = vt + ((size_t)h * HD + od) * S_LEN + s0 + os;
    #pragma unroll
    for (int i8 = 0; i8 < 2; i8++) {
        us8 vv;
        #pragma unroll
        for (int j = 0; j < 8; j++) vv[j] = ot[8*i8+j];
        *(us8*)(op + 8*i8) = vv;
    }
}

// ---------------------------------------------------------------------------
// RoPE in place on bf16 qkv; q additionally scaled by 1/sqrt(D)*log2e.
// ---------------------------------------------------------------------------
__global__ __launch_bounds__(256)
void rope_bf16_kernel(u16* __restrict__ qkvb) {
    const int idx = blockIdx.x * blockDim.x + threadIdx.x;
    const int i = idx & 31;
    const int h = (idx >> 5) & (NH - 1);
    const int s = idx >> 9;

    const float inv_freq = exp2f(-(float)i * (13.287712379549449f / 32.0f));
    float sn, cs;
    sincosf((float)s * inv_freq, &sn, &cs);
    const float SC = 0.125f * 1.44269504088896f;

    size_t base = (size_t)s * E3 + h * HD;
    {
        float t1 = bf2f(qkvb[base + i]), t2 = bf2f(qkvb[base + i + 32]);
        qkvb[base + i]      = f2bf((t1 * cs - t2 * sn) * SC);
        qkvb[base + i + 32] = f2bf((t2 * cs + t1 * sn) * SC);
    }
    base += EMB;
    {
        float t1 = bf2f(qkvb[base + i]), t2 = bf2f(qkvb[base + i + 32]);
        qkvb[base + i]      = f2bf(t1 * cs - t2 * sn);
        qkvb[base + i + 32] = f2bf(t2 * cs + t1 * sn);
    }
}

// ---------------------------------------------------------------------------
// bf16 MFMA GEMM (m97 structure): C[M,N] = A[M,K] * Bt[N,K]^T + bias
// ---------------------------------------------------------------------------
template <int OUT_BF16>
__global__ __launch_bounds__(256, 2)
void gemm_bt_kernel(const u16* __restrict__ A, const u16* __restrict__ Bt,
                    const float* __restrict__ bias, void* __restrict__ Cv,
                    int M, int N, int K) {
    __shared__ u16 As[128][32];
    __shared__ u16 Bs[128][32];

    const int tid = threadIdx.x;
    const int w = tid >> 6, L = tid & 63;
    const int col = L & 15, quad = L >> 4;
    const int wm = w & 1, wn = w >> 1;
    const int m0 = blockIdx.x * 128, n0 = blockIdx.y * 128;

    ffrag acc[4][4];
    #pragma unroll
    for (int a = 0; a < 4; a++)
        #pragma unroll
        for (int b = 0; b < 4; b++)
            #pragma unroll
            for (int r = 0; r < 4; r++) acc[a][b][r] = 0.f;

    const int srow = L >> 2;
    const int schk = L & 3;

    for (int k0 = 0; k0 < K; k0 += 32) {
        __syncthreads();
        #pragma unroll
        for (int t = 0; t < 2; t++) {
            const int rg = (2 * w + t) * 16;
            gld16(A  + (size_t)(m0 + rg + srow) * K + k0 + schk * 8, &As[rg][0]);
            gld16(Bt + (size_t)(n0 + rg + srow) * K + k0 + schk * 8, &Bs[rg][0]);
        }
        __syncthreads();

        bfrag af[4], bf[4];
        #pragma unroll
        for (int mt = 0; mt < 4; mt++)
            af[mt] = *(const bfrag*)&As[64 * wm + 16 * mt + col][8 * quad];
        #pragma unroll
        for (int nt = 0; nt < 4; nt++)
            bf[nt] = *(const bfrag*)&Bs[64 * wn + 16 * nt + col][8 * quad];
        #pragma unroll
        for (int mt = 0; mt < 4; mt++)
            #pragma unroll
            for (int nt = 0; nt < 4; nt++)
                acc[mt][nt] = __builtin_amdgcn_mfma_f32_16x16x32_bf16(
                    af[mt], bf[nt], acc[mt][nt], 0, 0, 0);
    }

    float bv[4];
    #pragma unroll
    for (int nt = 0; nt < 4; nt++) bv[nt] = bias[n0 + 64 * wn + 16 * nt + col];

    #pragma unroll
    for (int mt = 0; mt < 4; mt++) {
        #pragma unroll
        for (int r = 0; r < 4; r++) {
            const int m = m0 + 64 * wm + 16 * mt + 4 * quad + r;
            #pragma unroll
            for (int nt = 0; nt < 4; nt++) {
                const int n = n0 + 64 * wn + 16 * nt + col;
                const float val = acc[mt][nt][r] + bv[nt];
                if (OUT_BF16) ((u16*)Cv)[(size_t)m * N + n] = f2bf(val);
                else          ((float*)Cv)[(size_t)m * N + n] = val;
            }
        }
    }
}

// ---------------------------------------------------------------------------
// flash3: balanced-pair flash attention.
// Block = pair of 64-q tiles (qt, 63-qt): uniform 65 k-tiles/block.
// 4 waves x 16 q.  S^T = K Q^T; O^T = V^T P^T.  Double-buffered K/V via
// global_load_lds (one barrier per k-tile); diagonal-only causal masking.
// ---------------------------------------------------------------------------
__global__ __launch_bounds__(256, 2)
void flash3_kernel(const u16* __restrict__ qkvb, const u16* __restrict__ vt,
                   u16* __restrict__ ctxb) {
    __shared__ u16 Qs[64][64];
    __shared__ u16 Ks[2][64][64];
    __shared__ u16 Vs[2][64][64];
    __shared__ u16 Ps[4][16][72];

    const int h = blockIdx.y;
    const int p = blockIdx.x;                 // pair index 0..31
    const int tid = threadIdx.x;
    const int w = tid >> 6, L = tid & 63;
    const int col = L & 15, quad = L >> 4;
    const int lr = L >> 3, lp = L & 7;
    const int lc = lp ^ lr;                   // swizzled chunk for staging

    #pragma unroll 1
    for (int phase = 0; phase < 2; phase++) {
        const int qi = phase ? (63 - p) : p;
        const int q0 = qi * 64;
        const int nt = qi + 1;

        // ---- stage Q tile + K/V tile 0 ----
        #pragma unroll
        for (int u = 0; u < 2; u++) {
            const int row = 16 * w + 8 * u;
            gld16(qkvb + (size_t)(q0 + row + lr) * E3 + h * HD + lc * 8,
                  &Qs[row][0]);
            gld16(qkvb + (size_t)(row + lr) * E3 + EMB + h * HD + lc * 8,
                  &Ks[0][row][0]);
            gld16(vt + ((size_t)h * HD + row + lr) * S_LEN + lc * 8,
                  &Vs[0][row][0]);
        }
        __syncthreads();

        bfrag qf[2];
        #pragma unroll
        for (int ks = 0; ks < 2; ks++)
            qf[ks] = *(const bfrag*)
                &Qs[16 * w + col][(((4 * ks + quad) ^ (col & 7)) * 8)];

        ffrag o[4];
        #pragma unroll
        for (int d4 = 0; d4 < 4; d4++)
            #pragma unroll
            for (int r = 0; r < 4; r++) o[d4][r] = 0.f;
        float m = -3.0e38f, l = 0.f;

        #pragma unroll 1
        for (int t = 0; t < nt; t++) {
            const int buf = t & 1;
            // prefetch next tile into the other buffer (before compute)
            if (t + 1 < nt) {
                const int kb = (t + 1) * 64;
                #pragma unroll
                for (int u = 0; u < 2; u++) {
                    const int row = 16 * w + 8 * u;
                    gld16(qkvb + (size_t)(kb + row + lr) * E3 + EMB + h * HD + lc * 8,
                          &Ks[buf ^ 1][row][0]);
                    gld16(vt + ((size_t)h * HD + row + lr) * S_LEN + kb + lc * 8,
                          &Vs[buf ^ 1][row][0]);
                }
            }

            // ---- S^T = K Q^T ----
            ffrag st[4];
            #pragma unroll
            for (int t4 = 0; t4 < 4; t4++)
                #pragma unroll
                for (int r = 0; r < 4; r++) st[t4][r] = 0.f;
            #pragma unroll
            for (int ks = 0; ks < 2; ks++) {
                bfrag kf[4];
                #pragma unroll
                for (int t4 = 0; t4 < 4; t4++)
                    kf[t4] = *(const bfrag*)
                        &Ks[buf][16 * t4 + col][(((4 * ks + quad) ^ (col & 7)) * 8)];
                #pragma unroll
                for (int t4 = 0; t4 < 4; t4++)
                    st[t4] = __builtin_amdgcn_mfma_f32_16x16x32_bf16(
                        kf[t4], qf[ks], st[t4], 0, 0, 0);
            }

            // ---- causal mask: only the diagonal tile needs it ----
            if (t == nt - 1) {
                const int qloc = 16 * w + col;   // q - q0 ; keys local = 16t4+4quad+r
                #pragma unroll
                for (int t4 = 0; t4 < 4; t4++) {
                    const int key0 = 16 * t4 + 4 * quad;
                    #pragma unroll
                    for (int r = 0; r < 4; r++)
                        if (key0 + r > qloc) st[t4][r] = -3.0e38f;
                }
            }

            // ---- online softmax (exp2 domain) ----
            float mx = fmaxf(fmaxf(fmaxf(st[0][0], st[0][1]), fmaxf(st[0][2], st[0][3])),
                             fmaxf(fmaxf(st[1][0], st[1][1]), fmaxf(st[1][2], st[1][3])));
            mx = fmaxf(mx, fmaxf(fmaxf(fmaxf(st[2][0], st[2][1]), fmaxf(st[2][2], st[2][3])),
                                 fmaxf(fmaxf(st[3][0], st[3][1]), fmaxf(st[3][2], st[3][3]))));
            mx = fmaxf(mx, __shfl_xor(mx, 16, 64));
            mx = fmaxf(mx, __shfl_xor(mx, 32, 64));

            const float mn = fmaxf(m, mx);
            const float corr = exp2f(m - mn);
            m = mn;
            l *= corr;
            #pragma unroll
            for (int d4 = 0; d4 < 4; d4++)
                #pragma unroll
                for (int r = 0; r < 4; r++) o[d4][r] *= corr;

            float sm = 0.f;
            #pragma unroll
            for (int t4 = 0; t4 < 4; t4++) {
                float pr[4];
                #pragma unroll
                for (int r = 0; r < 4; r++) {
                    pr[r] = exp2f(st[t4][r] - mn);
                    sm += pr[r];
                }
                uint2 pk;
                pk.x = pack_bf16_trunc(pr[0], pr[1]);
                pk.y = pack_bf16_trunc(pr[2], pr[3]);
                *(uint2*)&Ps[w][col][16 * t4 + 4 * quad] = pk;
            }
            sm += __shfl_xor(sm, 16, 64);
            sm += __shfl_xor(sm, 32, 64);
            l += sm;

            // ---- O^T += V^T P^T ----
            #pragma unroll
            for (int ks = 0; ks < 2; ks++) {
                bfrag vf[4];
                #pragma unroll
                for (int d4 = 0; d4 < 4; d4++)
                    vf[d4] = *(const bfrag*)
                        &Vs[buf][16 * d4 + col][(((4 * ks + quad) ^ (col & 7)) * 8)];
                bfrag pf = *(const bfrag*)&Ps[w][col][32 * ks + 8 * quad];
                #pragma unroll
                for (int d4 = 0; d4 < 4; d4++)
                    o[d4] = __builtin_amdgcn_mfma_f32_16x16x32_bf16(
                        vf[d4], pf, o[d4], 0, 0, 0);
            }

            __syncthreads();   // compute done; next tile's loads drained here
        }

        // ---- epilogue: normalize, write ctx bf16 ----
        const float inv = 1.0f / l;
        const int qg = q0 + 16 * w + col;
        #pragma unroll
        for (int d4 = 0; d4 < 4; d4++) {
            us4 pk;
            #pragma unroll
            for (int r = 0; r < 4; r++) pk[r] = f2bf(o[d4][r] * inv);
            *(us4*)&ctxb[(size_t)qg * EMB + h * HD + 16 * d4 + 4 * quad] = pk;
        }
    }
}

// ---------------------------------------------------------------------------
extern "C" void kernel_launch(void* const* d_in, const int* in_sizes, int n_in,
                              void* d_out, int out_size, void* d_ws, size_t ws_size,
                              hipStream_t stream) {
    const float* x      = (const float*)d_in[0];
    const float* wqkv_w = (const float*)d_in[2];
    const float* wqkv_b = (const float*)d_in[3];
    const float* out_w  = (const float*)d_in[4];
    const float* out_b  = (const float*)d_in[5];
    float* out = (float*)d_out;

    u16* qkvb = (u16*)d_ws;                        // [4096][3072]
    u16* ctxb = qkvb + (size_t)S_LEN * E3;         // [4096][1024]
    u16* xb   = ctxb + (size_t)S_LEN * EMB;        // [4096][1024]
    u16* wt   = xb   + (size_t)S_LEN * EMB;        // [3072][1024]
    u16* owt  = wt   + (size_t)E3 * EMB;           // [1024][1024]
    u16* vtb  = owt  + (size_t)EMB * EMB;          // [16][64][4096]

    dim3 blk(256);

    cast_bf16_kernel<<<dim3(S_LEN * EMB / (256 * 8)), blk, 0, stream>>>(x, xb);
    transpose_cast_kernel<<<dim3(EMB / 64, E3 / 64), blk, 0, stream>>>(
        wqkv_w, wt, EMB, E3);
    transpose_cast_kernel<<<dim3(EMB / 64, EMB / 64), blk, 0, stream>>>(
        out_w, owt, EMB, EMB);

    gemm_bt_kernel<1><<<dim3(S_LEN / 128, E3 / 128), blk, 0, stream>>>(
        xb, wt, wqkv_b, qkvb, S_LEN, E3, EMB);

    rope_bf16_kernel<<<dim3(S_LEN * NH * 32 / 256), blk, 0, stream>>>(qkvb);
    transpose_v_kernel<<<dim3(S_LEN / 64, NH), blk, 0, stream>>>(qkvb, vtb);

    flash3_kernel<<<dim3(32, NH), blk, 0, stream>>>(qkvb, vtb, ctxb);

    gemm_bt_kernel<0><<<dim3(S_LEN / 128, EMB / 128), blk, 0, stream>>>(
        ctxb, owt, out_b, out, S_LEN, EMB, EMB);
}

// Round 5
// 269.927 us; speedup vs baseline: 10.6966x; 1.0425x over previous
//
#include <hip/hip_runtime.h>
#include <hip/hip_bf16.h>
#include <math.h>

#define S_LEN 4096
#define EMB   1024
#define E3    3072
#define NH    16
#define HD    64

typedef unsigned short u16;
typedef short          bfrag __attribute__((ext_vector_type(8)));  // 8 bf16
typedef float          ffrag __attribute__((ext_vector_type(4)));  // 4 f32
typedef unsigned short us8   __attribute__((ext_vector_type(8)));
typedef unsigned short us4   __attribute__((ext_vector_type(4)));

__device__ __forceinline__ u16 f2bf(float f) {
    union { float f; unsigned u; } v; v.f = f;
    unsigned r = v.u + 0x7fffu + ((v.u >> 16) & 1u);
    return (u16)(r >> 16);
}
__device__ __forceinline__ float bf2f(u16 b) {
    union { unsigned u; float f; } v; v.u = ((unsigned)b) << 16;
    return v.f;
}
// pack two f32 -> two bf16 (truncation) in one v_perm_b32
__device__ __forceinline__ unsigned pack_bf16_trunc(float lo, float hi) {
    union { float f; unsigned u; } a, b; a.f = lo; b.f = hi;
    return __builtin_amdgcn_perm(b.u, a.u, 0x07060302u);
}
// async global->LDS, 16B per lane; LDS dest = uniform base + lane*16
__device__ __forceinline__ void gld16(const void* g, void* l) {
    __builtin_amdgcn_global_load_lds(
        (const __attribute__((address_space(1))) unsigned int*)g,
        (__attribute__((address_space(3))) unsigned int*)l, 16, 0, 0);
}

// ---------------------------------------------------------------------------
// cast fp32 -> bf16, 8 elems/thread
// ---------------------------------------------------------------------------
__global__ __launch_bounds__(256)
void cast_bf16_kernel(const float* __restrict__ in, u16* __restrict__ out) {
    const size_t i = ((size_t)blockIdx.x * 256 + threadIdx.x) * 8;
    float4 a = *(const float4*)(in + i);
    float4 b = *(const float4*)(in + i + 4);
    us8 o;
    o[0]=f2bf(a.x); o[1]=f2bf(a.y); o[2]=f2bf(a.z); o[3]=f2bf(a.w);
    o[4]=f2bf(b.x); o[5]=f2bf(b.y); o[6]=f2bf(b.z); o[7]=f2bf(b.w);
    *(us8*)(out + i) = o;
}

// ---------------------------------------------------------------------------
// transpose+cast: in [R][C] fp32 -> out [C][R] bf16.  64x64 tiles.
// ---------------------------------------------------------------------------
__global__ __launch_bounds__(256)
void transpose_cast_kernel(const float* __restrict__ in, u16* __restrict__ out,
                           int R, int C) {
    __shared__ u16 T[64][72];
    const int r0 = blockIdx.x * 64, c0 = blockIdx.y * 64;
    const int t = threadIdx.x;
    const int rr = t >> 2, cc = (t & 3) * 16;

    const float* ip = in + (size_t)(r0 + rr) * C + c0 + cc;
    u16 tmp[16];
    #pragma unroll
    for (int i4 = 0; i4 < 4; i4++) {
        float4 v = ((const float4*)ip)[i4];
        tmp[4*i4+0]=f2bf(v.x); tmp[4*i4+1]=f2bf(v.y);
        tmp[4*i4+2]=f2bf(v.z); tmp[4*i4+3]=f2bf(v.w);
    }
    #pragma unroll
    for (int i8 = 0; i8 < 2; i8++) {
        us8 vv;
        #pragma unroll
        for (int j = 0; j < 8; j++) vv[j] = tmp[8*i8+j];
        *(us8*)&T[rr][cc + 8*i8] = vv;
    }
    __syncthreads();

    const int oc = t >> 2, orr = (t & 3) * 16;
    u16 ot[16];
    #pragma unroll
    for (int j = 0; j < 16; j++) ot[j] = T[orr + j][oc];
    u16* op = out + (size_t)(c0 + oc) * R + r0 + orr;
    #pragma unroll
    for (int i8 = 0; i8 < 2; i8++) {
        us8 vv;
        #pragma unroll
        for (int j = 0; j < 8; j++) vv[j] = ot[8*i8+j];
        *(us8*)(op + 8*i8) = vv;
    }
}

// ---------------------------------------------------------------------------
// transpose V part of qkvb [s][2048 + h*64 + d] -> vt[h][d][s]  (bf16->bf16)
// ---------------------------------------------------------------------------
__global__ __launch_bounds__(256)
void transpose_v_kernel(const u16* __restrict__ qkvb, u16* __restrict__ vt) {
    __shared__ u16 T[64][72];
    const int s0 = blockIdx.x * 64, h = blockIdx.y;
    const int t = threadIdx.x;
    const int rr = t >> 2, cc = (t & 3) * 16;

    const u16* ip = qkvb + (size_t)(s0 + rr) * E3 + 2 * EMB + h * HD + cc;
    *(us8*)&T[rr][cc]     = *(const us8*)ip;
    *(us8*)&T[rr][cc + 8] = *(const us8*)(ip + 8);
    __syncthreads();

    const int od = t >> 2, os = (t & 3) * 16;
    u16 ot[16];
    #pragma unroll
    for (int j = 0; j < 16; j++) ot[j] = T[os + j][od];
    u16* op = vt + ((size_t)h * HD + od) * S_LEN + s0 + os;
    #pragma unroll
    for (int i8 = 0; i8 < 2; i8++) {
        us8 vv;
        #pragma unroll
        for (int j = 0; j < 8; j++) vv[j] = ot[8*i8+j];
        *(us8*)(op + 8*i8) = vv;
    }
}

// ---------------------------------------------------------------------------
// RoPE in place on bf16 qkv; q additionally scaled by 1/sqrt(D)*log2e.
// ---------------------------------------------------------------------------
__global__ __launch_bounds__(256)
void rope_bf16_kernel(u16* __restrict__ qkvb) {
    const int idx = blockIdx.x * blockDim.x + threadIdx.x;
    const int i = idx & 31;
    const int h = (idx >> 5) & (NH - 1);
    const int s = idx >> 9;

    const float inv_freq = exp2f(-(float)i * (13.287712379549449f / 32.0f));
    float sn, cs;
    sincosf((float)s * inv_freq, &sn, &cs);
    const float SC = 0.125f * 1.44269504088896f;

    size_t base = (size_t)s * E3 + h * HD;
    {
        float t1 = bf2f(qkvb[base + i]), t2 = bf2f(qkvb[base + i + 32]);
        qkvb[base + i]      = f2bf((t1 * cs - t2 * sn) * SC);
        qkvb[base + i + 32] = f2bf((t2 * cs + t1 * sn) * SC);
    }
    base += EMB;
    {
        float t1 = bf2f(qkvb[base + i]), t2 = bf2f(qkvb[base + i + 32]);
        qkvb[base + i]      = f2bf(t1 * cs - t2 * sn);
        qkvb[base + i + 32] = f2bf(t2 * cs + t1 * sn);
    }
}

// ---------------------------------------------------------------------------
// bf16 MFMA GEMM (m97 structure): C[M,N] = A[M,K] * Bt[N,K]^T + bias
// ---------------------------------------------------------------------------
template <int OUT_BF16>
__global__ __launch_bounds__(256, 2)
void gemm_bt_kernel(const u16* __restrict__ A, const u16* __restrict__ Bt,
                    const float* __restrict__ bias, void* __restrict__ Cv,
                    int M, int N, int K) {
    __shared__ u16 As[128][32];
    __shared__ u16 Bs[128][32];

    const int tid = threadIdx.x;
    const int w = tid >> 6, L = tid & 63;
    const int col = L & 15, quad = L >> 4;
    const int wm = w & 1, wn = w >> 1;
    const int m0 = blockIdx.x * 128, n0 = blockIdx.y * 128;

    ffrag acc[4][4];
    #pragma unroll
    for (int a = 0; a < 4; a++)
        #pragma unroll
        for (int b = 0; b < 4; b++)
            #pragma unroll
            for (int r = 0; r < 4; r++) acc[a][b][r] = 0.f;

    const int srow = L >> 2;
    const int schk = L & 3;

    for (int k0 = 0; k0 < K; k0 += 32) {
        __syncthreads();
        #pragma unroll
        for (int t = 0; t < 2; t++) {
            const int rg = (2 * w + t) * 16;
            gld16(A  + (size_t)(m0 + rg + srow) * K + k0 + schk * 8, &As[rg][0]);
            gld16(Bt + (size_t)(n0 + rg + srow) * K + k0 + schk * 8, &Bs[rg][0]);
        }
        __syncthreads();

        bfrag af[4], bf[4];
        #pragma unroll
        for (int mt = 0; mt < 4; mt++)
            af[mt] = *(const bfrag*)&As[64 * wm + 16 * mt + col][8 * quad];
        #pragma unroll
        for (int nt = 0; nt < 4; nt++)
            bf[nt] = *(const bfrag*)&Bs[64 * wn + 16 * nt + col][8 * quad];
        #pragma unroll
        for (int mt = 0; mt < 4; mt++)
            #pragma unroll
            for (int nt = 0; nt < 4; nt++)
                acc[mt][nt] = __builtin_amdgcn_mfma_f32_16x16x32_bf16(
                    af[mt], bf[nt], acc[mt][nt], 0, 0, 0);
    }

    float bv[4];
    #pragma unroll
    for (int nt = 0; nt < 4; nt++) bv[nt] = bias[n0 + 64 * wn + 16 * nt + col];

    #pragma unroll
    for (int mt = 0; mt < 4; mt++) {
        #pragma unroll
        for (int r = 0; r < 4; r++) {
            const int m = m0 + 64 * wm + 16 * mt + 4 * quad + r;
            #pragma unroll
            for (int nt = 0; nt < 4; nt++) {
                const int n = n0 + 64 * wn + 16 * nt + col;
                const float val = acc[mt][nt][r] + bv[nt];
                if (OUT_BF16) ((u16*)Cv)[(size_t)m * N + n] = f2bf(val);
                else          ((float*)Cv)[(size_t)m * N + n] = val;
            }
        }
    }
}

// ---------------------------------------------------------------------------
// flash4: balanced-pair flash attention, static-max softmax.
// Block = pair of 64-q tiles (qt, 63-qt): uniform 65 k-tiles/block.
// 4 waves x 16 q.  S^T = K Q^T; O^T = V^T P^T.  Double-buffered K/V via
// global_load_lds; diagonal-only masking; softmax shift is a CONSTANT
// (softmax is shift-invariant; scores |s|<~6 in exp2 domain, fp32 range
// +-126 gives huge margin), deleting the online-max machinery entirely.
// l-reduction deferred to epilogue.  XCD-swizzled head assignment.
// ---------------------------------------------------------------------------
#define M0 16.0f

__global__ __launch_bounds__(256, 2)
void flash4_kernel(const u16* __restrict__ qkvb, const u16* __restrict__ vt,
                   u16* __restrict__ ctxb) {
    __shared__ u16 Qs[64][64];
    __shared__ u16 Ks[2][64][64];
    __shared__ u16 Vs[2][64][64];
    __shared__ u16 Ps[4][16][72];

    // XCD swizzle: block->XCD is id%8 (8 XCDs); give each XCD 2 heads so its
    // 4 MiB L2 holds the whole K/V working set (~2 MB).
    const int id = blockIdx.x;                 // 0..511
    const int h = (id & 7) + ((id >> 8) << 3); // 2 heads per XCD
    const int p = (id >> 3) & 31;              // pair index 0..31

    const int tid = threadIdx.x;
    const int w = tid >> 6, L = tid & 63;
    const int col = L & 15, quad = L >> 4;
    const int lr = L >> 3, lp = L & 7;
    const int lc = lp ^ lr;                    // swizzled chunk for staging

    // per-lane staging offsets (row u=0; u=1 is +8 rows)
    const size_t kArow = (size_t)(16 * w + lr) * E3 + EMB + h * HD + lc * 8;
    const size_t vArow = ((size_t)h * HD + 16 * w + lr) * S_LEN + lc * 8;

    #pragma unroll 1
    for (int phase = 0; phase < 2; phase++) {
        const int qi = phase ? (63 - p) : p;
        const int q0 = qi * 64;
        const int ntk = qi + 1;

        // ---- stage Q tile + K/V tile 0 ----
        #pragma unroll
        for (int u = 0; u < 2; u++) {
            const int row = 16 * w + 8 * u;
            gld16(qkvb + (size_t)(q0 + row + lr) * E3 + h * HD + lc * 8,
                  &Qs[row][0]);
            gld16(qkvb + kArow + (size_t)(8 * u) * E3, &Ks[0][row][0]);
            gld16(vt + vArow + (size_t)(8 * u) * S_LEN, &Vs[0][row][0]);
        }
        __syncthreads();

        bfrag qf[2];
        #pragma unroll
        for (int ks = 0; ks < 2; ks++)
            qf[ks] = *(const bfrag*)
                &Qs[16 * w + col][(((4 * ks + quad) ^ (col & 7)) * 8)];

        ffrag o[4];
        #pragma unroll
        for (int d4 = 0; d4 < 4; d4++)
            #pragma unroll
            for (int r = 0; r < 4; r++) o[d4][r] = 0.f;
        float lsum = 0.f;

        #pragma unroll 1
        for (int t = 0; t < ntk; t++) {
            const int buf = t & 1;
            // prefetch next tile into the other buffer (before compute)
            if (t + 1 < ntk) {
                const size_t ko = kArow + (size_t)(t + 1) * 64 * E3;
                const size_t vo = vArow + (size_t)(t + 1) * 64;
                #pragma unroll
                for (int u = 0; u < 2; u++) {
                    const int row = 16 * w + 8 * u;
                    gld16(qkvb + ko + (size_t)(8 * u) * E3, &Ks[buf ^ 1][row][0]);
                    gld16(vt + vo + (size_t)(8 * u) * S_LEN, &Vs[buf ^ 1][row][0]);
                }
            }

            // ---- S^T = K Q^T ----
            ffrag st[4];
            #pragma unroll
            for (int t4 = 0; t4 < 4; t4++)
                #pragma unroll
                for (int r = 0; r < 4; r++) st[t4][r] = 0.f;
            #pragma unroll
            for (int ks = 0; ks < 2; ks++) {
                bfrag kf[4];
                #pragma unroll
                for (int t4 = 0; t4 < 4; t4++)
                    kf[t4] = *(const bfrag*)
                        &Ks[buf][16 * t4 + col][(((4 * ks + quad) ^ (col & 7)) * 8)];
                #pragma unroll
                for (int t4 = 0; t4 < 4; t4++)
                    st[t4] = __builtin_amdgcn_mfma_f32_16x16x32_bf16(
                        kf[t4], qf[ks], st[t4], 0, 0, 0);
            }

            // ---- causal mask: only the diagonal tile ----
            if (t == ntk - 1) {
                const int qloc = 16 * w + col;
                #pragma unroll
                for (int t4 = 0; t4 < 4; t4++) {
                    const int key0 = 16 * t4 + 4 * quad;
                    #pragma unroll
                    for (int r = 0; r < 4; r++)
                        if (key0 + r > qloc) st[t4][r] = -3.0e38f;
                }
            }

            // ---- static-shift softmax: p = exp2(s - M0) ----
            #pragma unroll
            for (int t4 = 0; t4 < 4; t4++) {
                float pr[4];
                #pragma unroll
                for (int r = 0; r < 4; r++) {
                    pr[r] = exp2f(st[t4][r] - M0);
                    lsum += pr[r];
                }
                uint2 pk;
                pk.x = pack_bf16_trunc(pr[0], pr[1]);
                pk.y = pack_bf16_trunc(pr[2], pr[3]);
                *(uint2*)&Ps[w][col][16 * t4 + 4 * quad] = pk;
            }

            // ---- O^T += V^T P^T ----
            #pragma unroll
            for (int ks = 0; ks < 2; ks++) {
                bfrag vf[4];
                #pragma unroll
                for (int d4 = 0; d4 < 4; d4++)
                    vf[d4] = *(const bfrag*)
                        &Vs[buf][16 * d4 + col][(((4 * ks + quad) ^ (col & 7)) * 8)];
                bfrag pf = *(const bfrag*)&Ps[w][col][32 * ks + 8 * quad];
                #pragma unroll
                for (int d4 = 0; d4 < 4; d4++)
                    o[d4] = __builtin_amdgcn_mfma_f32_16x16x32_bf16(
                        vf[d4], pf, o[d4], 0, 0, 0);
            }

            __syncthreads();   // compute done; next tile's loads drained here
        }

        // ---- epilogue: complete l across quads, normalize, write bf16 ----
        lsum += __shfl_xor(lsum, 16, 64);
        lsum += __shfl_xor(lsum, 32, 64);
        const float inv = 1.0f / lsum;
        const int qg = q0 + 16 * w + col;
        #pragma unroll
        for (int d4 = 0; d4 < 4; d4++) {
            us4 pk;
            #pragma unroll
            for (int r = 0; r < 4; r++) pk[r] = f2bf(o[d4][r] * inv);
            *(us4*)&ctxb[(size_t)qg * EMB + h * HD + 16 * d4 + 4 * quad] = pk;
        }
    }
}

// ---------------------------------------------------------------------------
extern "C" void kernel_launch(void* const* d_in, const int* in_sizes, int n_in,
                              void* d_out, int out_size, void* d_ws, size_t ws_size,
                              hipStream_t stream) {
    const float* x      = (const float*)d_in[0];
    const float* wqkv_w = (const float*)d_in[2];
    const float* wqkv_b = (const float*)d_in[3];
    const float* out_w  = (const float*)d_in[4];
    const float* out_b  = (const float*)d_in[5];
    float* out = (float*)d_out;

    u16* qkvb = (u16*)d_ws;                        // [4096][3072]
    u16* ctxb = qkvb + (size_t)S_LEN * E3;         // [4096][1024]
    u16* xb   = ctxb + (size_t)S_LEN * EMB;        // [4096][1024]
    u16* wt   = xb   + (size_t)S_LEN * EMB;        // [3072][1024]
    u16* owt  = wt   + (size_t)E3 * EMB;           // [1024][1024]
    u16* vtb  = owt  + (size_t)EMB * EMB;          // [16][64][4096]

    dim3 blk(256);

    cast_bf16_kernel<<<dim3(S_LEN * EMB / (256 * 8)), blk, 0, stream>>>(x, xb);
    transpose_cast_kernel<<<dim3(EMB / 64, E3 / 64), blk, 0, stream>>>(
        wqkv_w, wt, EMB, E3);
    transpose_cast_kernel<<<dim3(EMB / 64, EMB / 64), blk, 0, stream>>>(
        out_w, owt, EMB, EMB);

    gemm_bt_kernel<1><<<dim3(S_LEN / 128, E3 / 128), blk, 0, stream>>>(
        xb, wt, wqkv_b, qkvb, S_LEN, E3, EMB);

    rope_bf16_kernel<<<dim3(S_LEN * NH * 32 / 256), blk, 0, stream>>>(qkvb);
    transpose_v_kernel<<<dim3(S_LEN / 64, NH), blk, 0, stream>>>(qkvb, vtb);

    flash4_kernel<<<dim3(512), blk, 0, stream>>>(qkvb, vtb, ctxb);

    gemm_bt_kernel<0><<<dim3(S_LEN / 128, EMB / 128), blk, 0, stream>>>(
        ctxb, owt, out_b, out, S_LEN, EMB, EMB);
}

// Round 6
// 267.377 us; speedup vs baseline: 10.7986x; 1.0095x over previous
//
#include <hip/hip_runtime.h>
#include <hip/hip_bf16.h>
#include <math.h>

#define S_LEN 4096
#define EMB   1024
#define E3    3072
#define NH    16
#define HD    64

typedef unsigned short u16;
typedef short          bfrag __attribute__((ext_vector_type(8)));  // 8 bf16
typedef float          ffrag __attribute__((ext_vector_type(4)));  // 4 f32
typedef unsigned short us8   __attribute__((ext_vector_type(8)));
typedef unsigned short us4   __attribute__((ext_vector_type(4)));

__device__ __forceinline__ u16 f2bf(float f) {
    union { float f; unsigned u; } v; v.f = f;
    unsigned r = v.u + 0x7fffu + ((v.u >> 16) & 1u);
    return (u16)(r >> 16);
}
__device__ __forceinline__ float bf2f(u16 b) {
    union { unsigned u; float f; } v; v.u = ((unsigned)b) << 16;
    return v.f;
}
// pack two f32 -> two bf16 (truncation) in one v_perm_b32
__device__ __forceinline__ unsigned pack_bf16_trunc(float lo, float hi) {
    union { float f; unsigned u; } a, b; a.f = lo; b.f = hi;
    return __builtin_amdgcn_perm(b.u, a.u, 0x07060302u);
}
// async global->LDS, 16B per lane; LDS dest = uniform base + lane*16
__device__ __forceinline__ void gld16(const void* g, void* l) {
    __builtin_amdgcn_global_load_lds(
        (const __attribute__((address_space(1))) unsigned int*)g,
        (__attribute__((address_space(3))) unsigned int*)l, 16, 0, 0);
}

// ---------------------------------------------------------------------------
// cast fp32 -> bf16, 8 elems/thread
// ---------------------------------------------------------------------------
__global__ __launch_bounds__(256)
void cast_bf16_kernel(const float* __restrict__ in, u16* __restrict__ out) {
    const size_t i = ((size_t)blockIdx.x * 256 + threadIdx.x) * 8;
    float4 a = *(const float4*)(in + i);
    float4 b = *(const float4*)(in + i + 4);
    us8 o;
    o[0]=f2bf(a.x); o[1]=f2bf(a.y); o[2]=f2bf(a.z); o[3]=f2bf(a.w);
    o[4]=f2bf(b.x); o[5]=f2bf(b.y); o[6]=f2bf(b.z); o[7]=f2bf(b.w);
    *(us8*)(out + i) = o;
}

// ---------------------------------------------------------------------------
// transpose+cast: in [R][C] fp32 -> out [C][R] bf16.  64x64 tiles.
// ---------------------------------------------------------------------------
__global__ __launch_bounds__(256)
void transpose_cast_kernel(const float* __restrict__ in, u16* __restrict__ out,
                           int R, int C) {
    __shared__ u16 T[64][72];
    const int r0 = blockIdx.x * 64, c0 = blockIdx.y * 64;
    const int t = threadIdx.x;
    const int rr = t >> 2, cc = (t & 3) * 16;

    const float* ip = in + (size_t)(r0 + rr) * C + c0 + cc;
    u16 tmp[16];
    #pragma unroll
    for (int i4 = 0; i4 < 4; i4++) {
        float4 v = ((const float4*)ip)[i4];
        tmp[4*i4+0]=f2bf(v.x); tmp[4*i4+1]=f2bf(v.y);
        tmp[4*i4+2]=f2bf(v.z); tmp[4*i4+3]=f2bf(v.w);
    }
    #pragma unroll
    for (int i8 = 0; i8 < 2; i8++) {
        us8 vv;
        #pragma unroll
        for (int j = 0; j < 8; j++) vv[j] = tmp[8*i8+j];
        *(us8*)&T[rr][cc + 8*i8] = vv;
    }
    __syncthreads();

    const int oc = t >> 2, orr = (t & 3) * 16;
    u16 ot[16];
    #pragma unroll
    for (int j = 0; j < 16; j++) ot[j] = T[orr + j][oc];
    u16* op = out + (size_t)(c0 + oc) * R + r0 + orr;
    #pragma unroll
    for (int i8 = 0; i8 < 2; i8++) {
        us8 vv;
        #pragma unroll
        for (int j = 0; j < 8; j++) vv[j] = ot[8*i8+j];
        *(us8*)(op + 8*i8) = vv;
    }
}

// ---------------------------------------------------------------------------
// transpose V part of qkvb [s][2048 + h*64 + d] -> vt[h][d][s]  (bf16->bf16)
// ---------------------------------------------------------------------------
__global__ __launch_bounds__(256)
void transpose_v_kernel(const u16* __restrict__ qkvb, u16* __restrict__ vt) {
    __shared__ u16 T[64][72];
    const int s0 = blockIdx.x * 64, h = blockIdx.y;
    const int t = threadIdx.x;
    const int rr = t >> 2, cc = (t & 3) * 16;

    const u16* ip = qkvb + (size_t)(s0 + rr) * E3 + 2 * EMB + h * HD + cc;
    *(us8*)&T[rr][cc]     = *(const us8*)ip;
    *(us8*)&T[rr][cc + 8] = *(const us8*)(ip + 8);
    __syncthreads();

    const int od = t >> 2, os = (t & 3) * 16;
    u16 ot[16];
    #pragma unroll
    for (int j = 0; j < 16; j++) ot[j] = T[os + j][od];
    u16* op = vt + ((size_t)h * HD + od) * S_LEN + s0 + os;
    #pragma unroll
    for (int i8 = 0; i8 < 2; i8++) {
        us8 vv;
        #pragma unroll
        for (int j = 0; j < 8; j++) vv[j] = ot[8*i8+j];
        *(us8*)(op + 8*i8) = vv;
    }
}

// ---------------------------------------------------------------------------
// RoPE in place on bf16 qkv; q additionally scaled by 1/sqrt(D)*log2e.
// ---------------------------------------------------------------------------
__global__ __launch_bounds__(256)
void rope_bf16_kernel(u16* __restrict__ qkvb) {
    const int idx = blockIdx.x * blockDim.x + threadIdx.x;
    const int i = idx & 31;
    const int h = (idx >> 5) & (NH - 1);
    const int s = idx >> 9;

    const float inv_freq = exp2f(-(float)i * (13.287712379549449f / 32.0f));
    float sn, cs;
    sincosf((float)s * inv_freq, &sn, &cs);
    const float SC = 0.125f * 1.44269504088896f;

    size_t base = (size_t)s * E3 + h * HD;
    {
        float t1 = bf2f(qkvb[base + i]), t2 = bf2f(qkvb[base + i + 32]);
        qkvb[base + i]      = f2bf((t1 * cs - t2 * sn) * SC);
        qkvb[base + i + 32] = f2bf((t2 * cs + t1 * sn) * SC);
    }
    base += EMB;
    {
        float t1 = bf2f(qkvb[base + i]), t2 = bf2f(qkvb[base + i + 32]);
        qkvb[base + i]      = f2bf(t1 * cs - t2 * sn);
        qkvb[base + i + 32] = f2bf(t2 * cs + t1 * sn);
    }
}

// ---------------------------------------------------------------------------
// bf16 MFMA GEMM, double-buffered: C[M,N] = A[M,K] * Bt[N,K]^T + bias
// 128x128 tile, BK=32; prefetch k+1 while computing k; one barrier/step.
// ---------------------------------------------------------------------------
template <int OUT_BF16>
__global__ __launch_bounds__(256, 2)
void gemm_bt_kernel(const u16* __restrict__ A, const u16* __restrict__ Bt,
                    const float* __restrict__ bias, void* __restrict__ Cv,
                    int M, int N, int K) {
    __shared__ u16 As[2][128][32];
    __shared__ u16 Bs[2][128][32];

    const int tid = threadIdx.x;
    const int w = tid >> 6, L = tid & 63;
    const int col = L & 15, quad = L >> 4;
    const int wm = w & 1, wn = w >> 1;
    const int m0 = blockIdx.x * 128, n0 = blockIdx.y * 128;

    ffrag acc[4][4];
    #pragma unroll
    for (int a = 0; a < 4; a++)
        #pragma unroll
        for (int b = 0; b < 4; b++)
            #pragma unroll
            for (int r = 0; r < 4; r++) acc[a][b][r] = 0.f;

    const int srow = L >> 2;
    const int schk = L & 3;

    // prologue: stage k=0 into buf 0
    #pragma unroll
    for (int t = 0; t < 2; t++) {
        const int rg = (2 * w + t) * 16;
        gld16(A  + (size_t)(m0 + rg + srow) * K + schk * 8, &As[0][rg][0]);
        gld16(Bt + (size_t)(n0 + rg + srow) * K + schk * 8, &Bs[0][rg][0]);
    }
    __syncthreads();

    int buf = 0;
    for (int k0 = 0; k0 < K; k0 += 32, buf ^= 1) {
        // prefetch next k-tile into alternate buffer
        if (k0 + 32 < K) {
            #pragma unroll
            for (int t = 0; t < 2; t++) {
                const int rg = (2 * w + t) * 16;
                gld16(A  + (size_t)(m0 + rg + srow) * K + k0 + 32 + schk * 8,
                      &As[buf ^ 1][rg][0]);
                gld16(Bt + (size_t)(n0 + rg + srow) * K + k0 + 32 + schk * 8,
                      &Bs[buf ^ 1][rg][0]);
            }
        }

        bfrag af[4], bf[4];
        #pragma unroll
        for (int mt = 0; mt < 4; mt++)
            af[mt] = *(const bfrag*)&As[buf][64 * wm + 16 * mt + col][8 * quad];
        #pragma unroll
        for (int nt = 0; nt < 4; nt++)
            bf[nt] = *(const bfrag*)&Bs[buf][64 * wn + 16 * nt + col][8 * quad];
        #pragma unroll
        for (int mt = 0; mt < 4; mt++)
            #pragma unroll
            for (int nt = 0; nt < 4; nt++)
                acc[mt][nt] = __builtin_amdgcn_mfma_f32_16x16x32_bf16(
                    af[mt], bf[nt], acc[mt][nt], 0, 0, 0);

        __syncthreads();
    }

    float bv[4];
    #pragma unroll
    for (int nt = 0; nt < 4; nt++) bv[nt] = bias[n0 + 64 * wn + 16 * nt + col];

    #pragma unroll
    for (int mt = 0; mt < 4; mt++) {
        #pragma unroll
        for (int r = 0; r < 4; r++) {
            const int m = m0 + 64 * wm + 16 * mt + 4 * quad + r;
            #pragma unroll
            for (int nt = 0; nt < 4; nt++) {
                const int n = n0 + 64 * wn + 16 * nt + col;
                const float val = acc[mt][nt][r] + bv[nt];
                if (OUT_BF16) ((u16*)Cv)[(size_t)m * N + n] = f2bf(val);
                else          ((float*)Cv)[(size_t)m * N + n] = val;
            }
        }
    }
}

// ---------------------------------------------------------------------------
// flash5: single 64-q blocks, 1024 blocks (all resident at 4 blocks/CU).
// 4 waves x 16 q.  S^T = K Q^T; O^T = V^T P^T.  Double-buffered K/V via
// global_load_lds; diagonal-only masking; NO max-shift (softmax is
// shift-invariant, scores |s|<~6); l computed by an all-ones-A MFMA
// (D[m][q] = sum_k P[q][k]) so no per-tile VALU reduction at all.
// P overlays the dead Q region per wave (16B-chunk XOR swizzle, stride 64).
// Zigzag qi mapping balances per-CU work under round-robin dispatch;
// id%8 is the XCD -> 2 heads per XCD keeps K/V in its 4 MiB L2.
// ---------------------------------------------------------------------------
__global__ __launch_bounds__(256, 4)
void flash5_kernel(const u16* __restrict__ qkvb, const u16* __restrict__ vt,
                   u16* __restrict__ ctxb) {
    __shared__ u16 QP[4][16][64];     // per-wave: Q rows, then P (swizzled)
    __shared__ u16 Ks[2][64][64];
    __shared__ u16 Vs[2][64][64];

    const int id = blockIdx.x;                    // 0..1023
    const int j  = (id >> 3) & 63;
    const int h  = (id & 7) | ((id >> 9) << 3);   // 2 heads per XCD
    const int qi = (j < 32) ? j : 95 - j;         // zigzag: j and j^32 sum to 63
    const int q0 = qi * 64;
    const int ntk = qi + 1;

    const int tid = threadIdx.x;
    const int w = tid >> 6, L = tid & 63;
    const int col = L & 15, quad = L >> 4;
    const int lr = L >> 3, lp = L & 7;
    const int lc = lp ^ lr;                       // swizzled chunk for staging

    const size_t kArow = (size_t)(16 * w + lr) * E3 + EMB + h * HD + lc * 8;
    const size_t vArow = ((size_t)h * HD + 16 * w + lr) * S_LEN + lc * 8;

    // ---- stage Q (own wave's 16 rows) + K/V tile 0 ----
    #pragma unroll
    for (int u = 0; u < 2; u++) {
        gld16(qkvb + (size_t)(q0 + 16 * w + 8 * u + lr) * E3 + h * HD + lc * 8,
              &QP[w][8 * u][0]);
        gld16(qkvb + kArow + (size_t)(8 * u) * E3, &Ks[0][16 * w + 8 * u][0]);
        gld16(vt + vArow + (size_t)(8 * u) * S_LEN, &Vs[0][16 * w + 8 * u][0]);
    }
    __syncthreads();

    bfrag qf[2];
    #pragma unroll
    for (int ks = 0; ks < 2; ks++)
        qf[ks] = *(const bfrag*)
            ((const char*)&QP[w][col][0] + 16 * ((4 * ks + quad) ^ (col & 7)));

    bfrag ones;
    #pragma unroll
    for (int i = 0; i < 8; i++) ones[i] = (short)0x3F80;

    ffrag o[4], ol;
    #pragma unroll
    for (int d4 = 0; d4 < 4; d4++)
        #pragma unroll
        for (int r = 0; r < 4; r++) o[d4][r] = 0.f;
    #pragma unroll
    for (int r = 0; r < 4; r++) ol[r] = 0.f;

    #pragma unroll 1
    for (int t = 0; t < ntk; t++) {
        const int buf = t & 1;
        // prefetch next k-tile into the other buffer (before compute)
        if (t + 1 < ntk) {
            const size_t ko = kArow + (size_t)(t + 1) * 64 * E3;
            const size_t vo = vArow + (size_t)(t + 1) * 64;
            #pragma unroll
            for (int u = 0; u < 2; u++) {
                gld16(qkvb + ko + (size_t)(8 * u) * E3, &Ks[buf ^ 1][16 * w + 8 * u][0]);
                gld16(vt + vo + (size_t)(8 * u) * S_LEN, &Vs[buf ^ 1][16 * w + 8 * u][0]);
            }
        }

        // ---- S^T = K Q^T ----
        ffrag st[4];
        #pragma unroll
        for (int t4 = 0; t4 < 4; t4++)
            #pragma unroll
            for (int r = 0; r < 4; r++) st[t4][r] = 0.f;
        #pragma unroll
        for (int ks = 0; ks < 2; ks++) {
            bfrag kf[4];
            #pragma unroll
            for (int t4 = 0; t4 < 4; t4++)
                kf[t4] = *(const bfrag*)
                    &Ks[buf][16 * t4 + col][(((4 * ks + quad) ^ (col & 7)) * 8)];
            #pragma unroll
            for (int t4 = 0; t4 < 4; t4++)
                st[t4] = __builtin_amdgcn_mfma_f32_16x16x32_bf16(
                    kf[t4], qf[ks], st[t4], 0, 0, 0);
        }

        // ---- causal mask: only the diagonal tile ----
        if (t == ntk - 1) {
            const int qloc = 16 * w + col;
            #pragma unroll
            for (int t4 = 0; t4 < 4; t4++) {
                const int key0 = 16 * t4 + 4 * quad;
                #pragma unroll
                for (int r = 0; r < 4; r++)
                    if (key0 + r > qloc) st[t4][r] = -3.0e38f;
            }
        }

        // ---- softmax numerator: p = exp2(s), no shift ----
        #pragma unroll
        for (int t4 = 0; t4 < 4; t4++) {
            float pr[4];
            #pragma unroll
            for (int r = 0; r < 4; r++) pr[r] = exp2f(st[t4][r]);
            uint2 pk;
            pk.x = pack_bf16_trunc(pr[0], pr[1]);
            pk.y = pack_bf16_trunc(pr[2], pr[3]);
            // 16B-chunk XOR swizzle, row = col, stride 64
            const int c2 = (2 * t4 + (quad >> 1)) ^ (col & 7);
            *(uint2*)((char*)&QP[w][col][0] + 16 * c2 + 8 * (quad & 1)) = pk;
        }

        // ---- O^T += V^T P^T ;  l += 1^T P^T (ones-MFMA) ----
        #pragma unroll
        for (int ks = 0; ks < 2; ks++) {
            bfrag vf[4];
            #pragma unroll
            for (int d4 = 0; d4 < 4; d4++)
                vf[d4] = *(const bfrag*)
                    &Vs[buf][16 * d4 + col][(((4 * ks + quad) ^ (col & 7)) * 8)];
            bfrag pf = *(const bfrag*)
                ((const char*)&QP[w][col][0] + 16 * ((4 * ks + quad) ^ (col & 7)));
            #pragma unroll
            for (int d4 = 0; d4 < 4; d4++)
                o[d4] = __builtin_amdgcn_mfma_f32_16x16x32_bf16(
                    vf[d4], pf, o[d4], 0, 0, 0);
            ol = __builtin_amdgcn_mfma_f32_16x16x32_bf16(ones, pf, ol, 0, 0, 0);
        }

        __syncthreads();   // compute done; next tile's loads drained here
    }

    // ---- epilogue: l is in every reg of ol for this lane's q ----
    const float inv = 1.0f / ol[0];
    const int qg = q0 + 16 * w + col;
    #pragma unroll
    for (int d4 = 0; d4 < 4; d4++) {
        us4 pk;
        #pragma unroll
        for (int r = 0; r < 4; r++) pk[r] = f2bf(o[d4][r] * inv);
        *(us4*)&ctxb[(size_t)qg * EMB + h * HD + 16 * d4 + 4 * quad] = pk;
    }
}

// ---------------------------------------------------------------------------
extern "C" void kernel_launch(void* const* d_in, const int* in_sizes, int n_in,
                              void* d_out, int out_size, void* d_ws, size_t ws_size,
                              hipStream_t stream) {
    const float* x      = (const float*)d_in[0];
    const float* wqkv_w = (const float*)d_in[2];
    const float* wqkv_b = (const float*)d_in[3];
    const float* out_w  = (const float*)d_in[4];
    const float* out_b  = (const float*)d_in[5];
    float* out = (float*)d_out;

    u16* qkvb = (u16*)d_ws;                        // [4096][3072]
    u16* ctxb = qkvb + (size_t)S_LEN * E3;         // [4096][1024]
    u16* xb   = ctxb + (size_t)S_LEN * EMB;        // [4096][1024]
    u16* wt   = xb   + (size_t)S_LEN * EMB;        // [3072][1024]
    u16* owt  = wt   + (size_t)E3 * EMB;           // [1024][1024]
    u16* vtb  = owt  + (size_t)EMB * EMB;          // [16][64][4096]

    dim3 blk(256);

    cast_bf16_kernel<<<dim3(S_LEN * EMB / (256 * 8)), blk, 0, stream>>>(x, xb);
    transpose_cast_kernel<<<dim3(EMB / 64, E3 / 64), blk, 0, stream>>>(
        wqkv_w, wt, EMB, E3);
    transpose_cast_kernel<<<dim3(EMB / 64, EMB / 64), blk, 0, stream>>>(
        out_w, owt, EMB, EMB);

    gemm_bt_kernel<1><<<dim3(S_LEN / 128, E3 / 128), blk, 0, stream>>>(
        xb, wt, wqkv_b, qkvb, S_LEN, E3, EMB);

    rope_bf16_kernel<<<dim3(S_LEN * NH * 32 / 256), blk, 0, stream>>>(qkvb);
    transpose_v_kernel<<<dim3(S_LEN / 64, NH), blk, 0, stream>>>(qkvb, vtb);

    flash5_kernel<<<dim3(1024), blk, 0, stream>>>(qkvb, vtb, ctxb);

    gemm_bt_kernel<0><<<dim3(S_LEN / 128, EMB / 128), blk, 0, stream>>>(
        ctxb, owt, out_b, out, S_LEN, EMB, EMB);
}

// Round 7
// 257.517 us; speedup vs baseline: 11.2120x; 1.0383x over previous
//
#include <hip/hip_runtime.h>
#include <hip/hip_bf16.h>
#include <math.h>

#define S_LEN 4096
#define EMB   1024
#define E3    3072
#define NH    16
#define HD    64

typedef unsigned short u16;
typedef short          bfrag __attribute__((ext_vector_type(8)));  // 8 bf16
typedef float          ffrag __attribute__((ext_vector_type(4)));  // 4 f32
typedef unsigned short us8   __attribute__((ext_vector_type(8)));
typedef unsigned short us4   __attribute__((ext_vector_type(4)));

__device__ __forceinline__ u16 f2bf(float f) {
    union { float f; unsigned u; } v; v.f = f;
    unsigned r = v.u + 0x7fffu + ((v.u >> 16) & 1u);
    return (u16)(r >> 16);
}
// pack two f32 -> two bf16 (truncation) in one v_perm_b32
__device__ __forceinline__ unsigned pack_bf16_trunc(float lo, float hi) {
    union { float f; unsigned u; } a, b; a.f = lo; b.f = hi;
    return __builtin_amdgcn_perm(b.u, a.u, 0x07060302u);
}
// async global->LDS, 16B per lane; LDS dest = uniform base + lane*16
__device__ __forceinline__ void gld16(const void* g, void* l) {
    __builtin_amdgcn_global_load_lds(
        (const __attribute__((address_space(1))) unsigned int*)g,
        (__attribute__((address_space(3))) unsigned int*)l, 16, 0, 0);
}

// ---------------------------------------------------------------------------
// cast fp32 -> bf16, 8 elems/thread
// ---------------------------------------------------------------------------
__global__ __launch_bounds__(256)
void cast_bf16_kernel(const float* __restrict__ in, u16* __restrict__ out) {
    const size_t i = ((size_t)blockIdx.x * 256 + threadIdx.x) * 8;
    float4 a = *(const float4*)(in + i);
    float4 b = *(const float4*)(in + i + 4);
    us8 o;
    o[0]=f2bf(a.x); o[1]=f2bf(a.y); o[2]=f2bf(a.z); o[3]=f2bf(a.w);
    o[4]=f2bf(b.x); o[5]=f2bf(b.y); o[6]=f2bf(b.z); o[7]=f2bf(b.w);
    *(us8*)(out + i) = o;
}

// ---------------------------------------------------------------------------
// transpose+cast: in [R][C] fp32 -> out [C][R] bf16.  64x64 tiles.
// ---------------------------------------------------------------------------
__global__ __launch_bounds__(256)
void transpose_cast_kernel(const float* __restrict__ in, u16* __restrict__ out,
                           int R, int C) {
    __shared__ u16 T[64][72];
    const int r0 = blockIdx.x * 64, c0 = blockIdx.y * 64;
    const int t = threadIdx.x;
    const int rr = t >> 2, cc = (t & 3) * 16;

    const float* ip = in + (size_t)(r0 + rr) * C + c0 + cc;
    u16 tmp[16];
    #pragma unroll
    for (int i4 = 0; i4 < 4; i4++) {
        float4 v = ((const float4*)ip)[i4];
        tmp[4*i4+0]=f2bf(v.x); tmp[4*i4+1]=f2bf(v.y);
        tmp[4*i4+2]=f2bf(v.z); tmp[4*i4+3]=f2bf(v.w);
    }
    #pragma unroll
    for (int i8 = 0; i8 < 2; i8++) {
        us8 vv;
        #pragma unroll
        for (int j = 0; j < 8; j++) vv[j] = tmp[8*i8+j];
        *(us8*)&T[rr][cc + 8*i8] = vv;
    }
    __syncthreads();

    const int oc = t >> 2, orr = (t & 3) * 16;
    u16 ot[16];
    #pragma unroll
    for (int j = 0; j < 16; j++) ot[j] = T[orr + j][oc];
    u16* op = out + (size_t)(c0 + oc) * R + r0 + orr;
    #pragma unroll
    for (int i8 = 0; i8 < 2; i8++) {
        us8 vv;
        #pragma unroll
        for (int j = 0; j < 8; j++) vv[j] = ot[8*i8+j];
        *(us8*)(op + 8*i8) = vv;
    }
}

// ---------------------------------------------------------------------------
// transpose V part of qkvb [s][2048 + h*64 + d] -> vt[h][d][s]  (bf16->bf16)
// ---------------------------------------------------------------------------
__global__ __launch_bounds__(256)
void transpose_v_kernel(const u16* __restrict__ qkvb, u16* __restrict__ vt) {
    __shared__ u16 T[64][72];
    const int s0 = blockIdx.x * 64, h = blockIdx.y;
    const int t = threadIdx.x;
    const int rr = t >> 2, cc = (t & 3) * 16;

    const u16* ip = qkvb + (size_t)(s0 + rr) * E3 + 2 * EMB + h * HD + cc;
    *(us8*)&T[rr][cc]     = *(const us8*)ip;
    *(us8*)&T[rr][cc + 8] = *(const us8*)(ip + 8);
    __syncthreads();

    const int od = t >> 2, os = (t & 3) * 16;
    u16 ot[16];
    #pragma unroll
    for (int j = 0; j < 16; j++) ot[j] = T[os + j][od];
    u16* op = vt + ((size_t)h * HD + od) * S_LEN + s0 + os;
    #pragma unroll
    for (int i8 = 0; i8 < 2; i8++) {
        us8 vv;
        #pragma unroll
        for (int j = 0; j < 8; j++) vv[j] = ot[8*i8+j];
        *(us8*)(op + 8*i8) = vv;
    }
}

// ---------------------------------------------------------------------------
// bf16 MFMA GEMM, double-buffered: C[M,N] = A[M,K] * Bt[N,K]^T + bias
// Tile 128 x (32*NT); 4 waves as 2m x 2n; wave does 4x NT 16x16x32 tiles.
// ROPE=1 (requires NT=4): fuse RoPE rotation into the epilogue. The wave's
// 64-wide n-span is one head; pairs (d, d+32) are acc[mt][nt]/acc[mt][nt+2]
// in the same lane. q columns (n<1024) also get the 0.125*log2e scale.
// ---------------------------------------------------------------------------
template <int OUT_BF16, int NT, int ROPE, int MINW>
__global__ __launch_bounds__(256, MINW)
void gemm_bt_kernel(const u16* __restrict__ A, const u16* __restrict__ Bt,
                    const float* __restrict__ bias, void* __restrict__ Cv,
                    int M, int N, int K) {
    constexpr int BN = 32 * NT;       // block n-span
    constexpr int WS = 16 * NT;       // wave n-span
    __shared__ u16 As[2][128][32];
    __shared__ u16 Bs[2][BN][32];

    const int tid = threadIdx.x;
    const int w = tid >> 6, L = tid & 63;
    const int col = L & 15, quad = L >> 4;
    const int wm = w & 1, wn = w >> 1;
    const int m0 = blockIdx.x * 128, n0 = blockIdx.y * BN;

    ffrag acc[4][NT];
    #pragma unroll
    for (int a = 0; a < 4; a++)
        #pragma unroll
        for (int b = 0; b < NT; b++)
            #pragma unroll
            for (int r = 0; r < 4; r++) acc[a][b][r] = 0.f;

    const int srow = L >> 2;
    const int schk = L & 3;

    // prologue: stage k=0 into buf 0
    #pragma unroll
    for (int t = 0; t < 2; t++) {
        const int rg = (2 * w + t) * 16;
        gld16(A + (size_t)(m0 + rg + srow) * K + schk * 8, &As[0][rg][0]);
    }
    #pragma unroll
    for (int t = 0; t < NT / 2; t++) {
        const int rg = (w * (NT / 2) + t) * 16;
        gld16(Bt + (size_t)(n0 + rg + srow) * K + schk * 8, &Bs[0][rg][0]);
    }
    __syncthreads();

    int buf = 0;
    for (int k0 = 0; k0 < K; k0 += 32, buf ^= 1) {
        if (k0 + 32 < K) {
            #pragma unroll
            for (int t = 0; t < 2; t++) {
                const int rg = (2 * w + t) * 16;
                gld16(A + (size_t)(m0 + rg + srow) * K + k0 + 32 + schk * 8,
                      &As[buf ^ 1][rg][0]);
            }
            #pragma unroll
            for (int t = 0; t < NT / 2; t++) {
                const int rg = (w * (NT / 2) + t) * 16;
                gld16(Bt + (size_t)(n0 + rg + srow) * K + k0 + 32 + schk * 8,
                      &Bs[buf ^ 1][rg][0]);
            }
        }

        bfrag af[4], bf[NT];
        #pragma unroll
        for (int mt = 0; mt < 4; mt++)
            af[mt] = *(const bfrag*)&As[buf][64 * wm + 16 * mt + col][8 * quad];
        #pragma unroll
        for (int nt = 0; nt < NT; nt++)
            bf[nt] = *(const bfrag*)&Bs[buf][WS * wn + 16 * nt + col][8 * quad];
        #pragma unroll
        for (int mt = 0; mt < 4; mt++)
            #pragma unroll
            for (int nt = 0; nt < NT; nt++)
                acc[mt][nt] = __builtin_amdgcn_mfma_f32_16x16x32_bf16(
                    af[mt], bf[nt], acc[mt][nt], 0, 0, 0);

        __syncthreads();
    }

    float bv[NT];
    #pragma unroll
    for (int nt = 0; nt < NT; nt++) bv[nt] = bias[n0 + WS * wn + 16 * nt + col];

    if (ROPE && n0 < 2 * EMB) {
        // q (n<1024) or k (1024..2047) region: rotate (d, d+32) pairs.
        const float SCq = (n0 < EMB) ? 0.125f * 1.44269504088896f : 1.0f;
        const float C = 13.287712379549449f / 32.0f;   // log2(10000)/32
        float invf[2];
        invf[0] = exp2f(-(float)col * C);
        invf[1] = exp2f(-(float)(col + 16) * C);
        #pragma unroll
        for (int mt = 0; mt < 4; mt++) {
            #pragma unroll
            for (int r = 0; r < 4; r++) {
                const int mrow = m0 + 64 * wm + 16 * mt + 4 * quad + r;
                const float fs = (float)mrow;
                u16* cp = (u16*)Cv + (size_t)mrow * N + n0 + 64 * wn + col;
                #pragma unroll
                for (int pr = 0; pr < 2; pr++) {
                    float sn, cs;
                    sincosf(fs * invf[pr], &sn, &cs);
                    const float t1 = acc[mt][pr][r] + bv[pr];
                    const float t2 = acc[mt][pr + 2][r] + bv[pr + 2];
                    cp[16 * pr]      = f2bf((t1 * cs - t2 * sn) * SCq);
                    cp[16 * pr + 32] = f2bf((t2 * cs + t1 * sn) * SCq);
                }
            }
        }
    } else {
        #pragma unroll
        for (int mt = 0; mt < 4; mt++) {
            #pragma unroll
            for (int r = 0; r < 4; r++) {
                const int m = m0 + 64 * wm + 16 * mt + 4 * quad + r;
                #pragma unroll
                for (int nt = 0; nt < NT; nt++) {
                    const int n = n0 + WS * wn + 16 * nt + col;
                    const float val = acc[mt][nt][r] + bv[nt];
                    if (OUT_BF16) ((u16*)Cv)[(size_t)m * N + n] = f2bf(val);
                    else          ((float*)Cv)[(size_t)m * N + n] = val;
                }
            }
        }
    }
}

// ---------------------------------------------------------------------------
// flash6: 128-q blocks, 32 q per wave (2 q-subtiles share every K/V fragment
// read -> ~1.7x less LDS traffic per unit work than 16 q/wave).  512 blocks,
// 2 blocks/CU.  S^T = K Q^T; O^T = V^T P^T; no-shift exp2 softmax; l via
// ones-MFMA; double-buffered K/V staging via global_load_lds; per-wave
// causal tile skip + mask on the per-wave diagonal tile only.
// Zigzag + hi-bit pairing => both resident blocks per CU sum to 68 tiles.
// id%8 = XCD -> 2 heads per XCD keeps K/V inside its 4 MiB L2.
// ---------------------------------------------------------------------------
__global__ __launch_bounds__(256, 2)
void flash6_kernel(const u16* __restrict__ qkvb, const u16* __restrict__ vt,
                   u16* __restrict__ ctxb) {
    __shared__ u16 QP[4][32][64];     // per-wave: Q rows, then P overlay
    __shared__ u16 Ks[2][64][64];
    __shared__ u16 Vs[2][64][64];

    const int id = blockIdx.x;                    // 0..511
    const int j  = (id >> 3) & 31;
    const int hi = id >> 8;                       // 0/1
    const int h  = (id & 7) | (hi << 3);          // 2 heads per XCD
    const int zig = (j < 16) ? j : 47 - j;        // pairs (j, j+16) sum 31
    const int qi  = hi ? (31 - zig) : zig;        // resident pair sums 31
    const int q0  = qi * 128;
    const int ntk = 2 * qi + 2;                   // 64-k tiles incl. diagonal

    const int tid = threadIdx.x;
    const int w = tid >> 6, L = tid & 63;
    const int col = L & 15, quad = L >> 4;
    const int lr = L >> 3, lp = L & 7;
    const int lc = lp ^ lr;                       // swizzled chunk for staging

    const int nwt = ntk - (w < 2 ? 1 : 0);        // this wave's compute tiles

    const size_t kArow = (size_t)(16 * w + lr) * E3 + EMB + h * HD + lc * 8;
    const size_t vArow = ((size_t)h * HD + 16 * w + lr) * S_LEN + lc * 8;

    // ---- stage Q (own wave's 32 rows) + K/V tile 0 ----
    #pragma unroll
    for (int u = 0; u < 4; u++)
        gld16(qkvb + (size_t)(q0 + 32 * w + 8 * u + lr) * E3 + h * HD + lc * 8,
              &QP[w][8 * u][0]);
    #pragma unroll
    for (int u = 0; u < 2; u++) {
        gld16(qkvb + kArow + (size_t)(8 * u) * E3, &Ks[0][16 * w + 8 * u][0]);
        gld16(vt + vArow + (size_t)(8 * u) * S_LEN, &Vs[0][16 * w + 8 * u][0]);
    }
    __syncthreads();

    bfrag qf[2][2];
    #pragma unroll
    for (int i = 0; i < 2; i++)
        #pragma unroll
        for (int ks = 0; ks < 2; ks++)
            qf[i][ks] = *(const bfrag*)
                ((const char*)&QP[w][16 * i + col][0] +
                 16 * ((4 * ks + quad) ^ (col & 7)));

    bfrag ones;
    #pragma unroll
    for (int i = 0; i < 8; i++) ones[i] = (short)0x3F80;

    ffrag o[4][2], ol[2];
    #pragma unroll
    for (int d4 = 0; d4 < 4; d4++)
        #pragma unroll
        for (int i = 0; i < 2; i++)
            #pragma unroll
            for (int r = 0; r < 4; r++) o[d4][i][r] = 0.f;
    #pragma unroll
    for (int i = 0; i < 2; i++)
        #pragma unroll
        for (int r = 0; r < 4; r++) ol[i][r] = 0.f;

    #pragma unroll 1
    for (int t = 0; t < ntk; t++) {
        const int buf = t & 1;
        // prefetch next k-tile into the other buffer (before compute)
        if (t + 1 < ntk) {
            const size_t ko = kArow + (size_t)(t + 1) * 64 * E3;
            const size_t vo = vArow + (size_t)(t + 1) * 64;
            #pragma unroll
            for (int u = 0; u < 2; u++) {
                gld16(qkvb + ko + (size_t)(8 * u) * E3,
                      &Ks[buf ^ 1][16 * w + 8 * u][0]);
                gld16(vt + vo + (size_t)(8 * u) * S_LEN,
                      &Vs[buf ^ 1][16 * w + 8 * u][0]);
            }
        }

        if (t < nwt) {
            // ---- S^T = K Q^T ----
            ffrag st[4][2];
            #pragma unroll
            for (int t4 = 0; t4 < 4; t4++)
                #pragma unroll
                for (int i = 0; i < 2; i++)
                    #pragma unroll
                    for (int r = 0; r < 4; r++) st[t4][i][r] = 0.f;
            #pragma unroll
            for (int ks = 0; ks < 2; ks++) {
                bfrag kf[4];
                #pragma unroll
                for (int t4 = 0; t4 < 4; t4++)
                    kf[t4] = *(const bfrag*)
                        &Ks[buf][16 * t4 + col][(((4 * ks + quad) ^ (col & 7)) * 8)];
                #pragma unroll
                for (int t4 = 0; t4 < 4; t4++)
                    #pragma unroll
                    for (int i = 0; i < 2; i++)
                        st[t4][i] = __builtin_amdgcn_mfma_f32_16x16x32_bf16(
                            kf[t4], qf[i][ks], st[t4][i], 0, 0, 0);
            }

            // ---- causal mask: only this wave's diagonal tile ----
            if (t == nwt - 1) {
                #pragma unroll
                for (int i = 0; i < 2; i++) {
                    const int qrel = 32 * (w & 1) + 16 * i + col;
                    #pragma unroll
                    for (int t4 = 0; t4 < 4; t4++) {
                        const int key0 = 16 * t4 + 4 * quad;
                        #pragma unroll
                        for (int r = 0; r < 4; r++)
                            if (key0 + r > qrel) st[t4][i][r] = -3.0e38f;
                    }
                }
            }

            // ---- softmax numerator: p = exp2(s), no shift ----
            #pragma unroll
            for (int i = 0; i < 2; i++) {
                const int prow = 16 * i + col;
                #pragma unroll
                for (int t4 = 0; t4 < 4; t4++) {
                    float pr[4];
                    #pragma unroll
                    for (int r = 0; r < 4; r++) pr[r] = exp2f(st[t4][i][r]);
                    uint2 pk;
                    pk.x = pack_bf16_trunc(pr[0], pr[1]);
                    pk.y = pack_bf16_trunc(pr[2], pr[3]);
                    const int c2 = (2 * t4 + (quad >> 1)) ^ (col & 7);
                    *(uint2*)((char*)&QP[w][prow][0] + 16 * c2 + 8 * (quad & 1)) = pk;
                }
            }

            // ---- O^T += V^T P^T ;  l += 1^T P^T ----
            #pragma unroll
            for (int ks = 0; ks < 2; ks++) {
                bfrag vf[4];
                #pragma unroll
                for (int d4 = 0; d4 < 4; d4++)
                    vf[d4] = *(const bfrag*)
                        &Vs[buf][16 * d4 + col][(((4 * ks + quad) ^ (col & 7)) * 8)];
                bfrag pf[2];
                #pragma unroll
                for (int i = 0; i < 2; i++)
                    pf[i] = *(const bfrag*)
                        ((const char*)&QP[w][16 * i + col][0] +
                         16 * ((4 * ks + quad) ^ (col & 7)));
                #pragma unroll
                for (int d4 = 0; d4 < 4; d4++)
                    #pragma unroll
                    for (int i = 0; i < 2; i++)
                        o[d4][i] = __builtin_amdgcn_mfma_f32_16x16x32_bf16(
                            vf[d4], pf[i], o[d4][i], 0, 0, 0);
                #pragma unroll
                for (int i = 0; i < 2; i++)
                    ol[i] = __builtin_amdgcn_mfma_f32_16x16x32_bf16(
                        ones, pf[i], ol[i], 0, 0, 0);
            }
        }

        __syncthreads();   // compute done; next tile's loads drained here
    }

    // ---- epilogue ----
    #pragma unroll
    for (int i = 0; i < 2; i++) {
        const float inv = 1.0f / ol[i][0];
        const int qg = q0 + 32 * w + 16 * i + col;
        #pragma unroll
        for (int d4 = 0; d4 < 4; d4++) {
            us4 pk;
            #pragma unroll
            for (int r = 0; r < 4; r++) pk[r] = f2bf(o[d4][i][r] * inv);
            *(us4*)&ctxb[(size_t)qg * EMB + h * HD + 16 * d4 + 4 * quad] = pk;
        }
    }
}

// ---------------------------------------------------------------------------
extern "C" void kernel_launch(void* const* d_in, const int* in_sizes, int n_in,
                              void* d_out, int out_size, void* d_ws, size_t ws_size,
                              hipStream_t stream) {
    const float* x      = (const float*)d_in[0];
    const float* wqkv_w = (const float*)d_in[2];
    const float* wqkv_b = (const float*)d_in[3];
    const float* out_w  = (const float*)d_in[4];
    const float* out_b  = (const float*)d_in[5];
    float* out = (float*)d_out;

    u16* qkvb = (u16*)d_ws;                        // [4096][3072]
    u16* ctxb = qkvb + (size_t)S_LEN * E3;         // [4096][1024]
    u16* xb   = ctxb + (size_t)S_LEN * EMB;        // [4096][1024]
    u16* wt   = xb   + (size_t)S_LEN * EMB;        // [3072][1024]
    u16* owt  = wt   + (size_t)E3 * EMB;           // [1024][1024]
    u16* vtb  = owt  + (size_t)EMB * EMB;          // [16][64][4096]

    dim3 blk(256);

    cast_bf16_kernel<<<dim3(S_LEN * EMB / (256 * 8)), blk, 0, stream>>>(x, xb);
    transpose_cast_kernel<<<dim3(EMB / 64, E3 / 64), blk, 0, stream>>>(
        wqkv_w, wt, EMB, E3);
    transpose_cast_kernel<<<dim3(EMB / 64, EMB / 64), blk, 0, stream>>>(
        out_w, owt, EMB, EMB);

    // QKV projection + fused RoPE (+ q pre-scale), 3 blocks/CU
    gemm_bt_kernel<1, 4, 1, 3><<<dim3(S_LEN / 128, E3 / 128), blk, 0, stream>>>(
        xb, wt, wqkv_b, qkvb, S_LEN, E3, EMB);

    transpose_v_kernel<<<dim3(S_LEN / 64, NH), blk, 0, stream>>>(qkvb, vtb);

    flash6_kernel<<<dim3(512), blk, 0, stream>>>(qkvb, vtb, ctxb);

    // output projection, 128x64 tiles -> 512 blocks (2/CU)
    gemm_bt_kernel<0, 2, 0, 2><<<dim3(S_LEN / 128, EMB / 64), blk, 0, stream>>>(
        ctxb, owt, out_b, out, S_LEN, EMB, EMB);
}